// Round 4
// baseline (1298.111 us; speedup 1.0000x reference)
//
#include <hip/hip_runtime.h>
#include <hip/hip_fp16.h>

#define NN 30000
#define NE 400000
#define NBUCK 59     // ceil(30000/512)
#define BPR 98       // blocks per relation in csr_binA: ceil(400000/4096)
#define EPB 4096     // edges per block in csr_binA
#define CAPREG 12288 // fixed slots per (rel,bucket) in binned scratch (mean 6827, sigma 82)
#define BCAP 12288   // LDS sort capacity in csr_binB

__constant__ int d_SRC[10] = {0,1,2,3,0,1,2,1,3,1};
__constant__ int d_DST[10] = {0,1,2,3,1,0,1,2,1,3};
// gather_agg2 relation order grouped by src type (L2 slice reuse): srcs 1,1,1,1,0,0,2,2,3,3
__constant__ int d_RORD[10] = {1,5,7,9,0,4,2,6,3,8};

// ---------------- fp32 tiled GEMM: C[M,N] = act(A)[M,K] @ B[K,N] + bias ----
// epi=0: store C (fp32). epi=1: tanh + column-sum -> atomicAdd into C[N] (colsum).
// epi=2: store C as fp16 (C reinterpreted as __half*).
template<int BN>
__global__ __launch_bounds__(256)
void gemm_k(const float* __restrict__ A, long sA,
            const float* __restrict__ B, long sB,
            const float* __restrict__ bias, long sBias,
            float* __restrict__ C, long sC,
            int M, int K, int N, int relu_a, int epi)
{
    constexpr int BM = 64, BK = 16;
    constexpr int TN = BN / 16;
    const int z = blockIdx.z;
    A += (long)z * sA;
    B += (long)z * sB;
    bias += (long)z * sBias;
    C += (long)z * sC;
    const int m0 = blockIdx.x * BM;
    const int n0 = blockIdx.y * BN;
    const int tid = threadIdx.x;

    __shared__ float As[BK][BM];
    __shared__ float Bs[BK][BN];

    const int ar = tid >> 2;
    const int ak = (tid & 3) << 2;
    const int bk = tid >> 4;
    const int bn = (tid & 15) * TN;
    const int tr = (tid >> 4) << 2;
    const int tc = (tid & 15) * TN;

    float acc[4][TN];
#pragma unroll
    for (int r = 0; r < 4; ++r)
#pragma unroll
        for (int j = 0; j < TN; ++j) acc[r][j] = 0.f;

    const int grow = m0 + ar;
    for (int k0 = 0; k0 < K; k0 += BK) {
        float av[4];
        if (grow < M) {
            const float* ap = A + (long)grow * K + k0 + ak;
            float4 u = *(const float4*)ap;
            av[0] = u.x; av[1] = u.y; av[2] = u.z; av[3] = u.w;
            if (relu_a) {
#pragma unroll
                for (int j = 0; j < 4; ++j) av[j] = fmaxf(av[j], 0.f);
            }
        } else {
            av[0] = av[1] = av[2] = av[3] = 0.f;
        }
        As[ak + 0][ar] = av[0]; As[ak + 1][ar] = av[1];
        As[ak + 2][ar] = av[2]; As[ak + 3][ar] = av[3];

        {
            const float* bp = B + (long)(k0 + bk) * N + n0 + bn;
            if constexpr (TN == 4) {
                float4 u = *(const float4*)bp;
                Bs[bk][bn + 0] = u.x; Bs[bk][bn + 1] = u.y;
                Bs[bk][bn + 2] = u.z; Bs[bk][bn + 3] = u.w;
            } else {
                float2 u = *(const float2*)bp;
                Bs[bk][bn + 0] = u.x; Bs[bk][bn + 1] = u.y;
            }
        }
        __syncthreads();
#pragma unroll
        for (int k = 0; k < BK; ++k) {
            float4 a4 = *(const float4*)&As[k][tr];
            float ar4[4] = {a4.x, a4.y, a4.z, a4.w};
            float bv[TN];
            if constexpr (TN == 4) {
                float4 b4 = *(const float4*)&Bs[k][tc];
                bv[0] = b4.x; bv[1] = b4.y; bv[2] = b4.z; bv[3] = b4.w;
            } else {
                float2 b2 = *(const float2*)&Bs[k][tc];
                bv[0] = b2.x; bv[1] = b2.y;
            }
#pragma unroll
            for (int r = 0; r < 4; ++r)
#pragma unroll
                for (int j = 0; j < TN; ++j)
                    acc[r][j] += ar4[r] * bv[j];
        }
        __syncthreads();
    }

    float biasv[TN];
#pragma unroll
    for (int j = 0; j < TN; ++j) biasv[j] = bias[n0 + tc + j];

    if (epi == 0) {
#pragma unroll
        for (int r = 0; r < 4; ++r) {
            int gr = m0 + tr + r;
            if (gr < M) {
                float* cp = C + (long)gr * N + n0 + tc;
#pragma unroll
                for (int j = 0; j < TN; ++j) cp[j] = acc[r][j] + biasv[j];
            }
        }
    } else if (epi == 2) {
        __half* Ch = (__half*)C;
#pragma unroll
        for (int r = 0; r < 4; ++r) {
            int gr = m0 + tr + r;
            if (gr < M) {
                __half* cp = Ch + (long)gr * N + n0 + tc;
#pragma unroll
                for (int j = 0; j < TN; j += 2) {
                    __half2 p = __floats2half2_rn(acc[r][j] + biasv[j],
                                                  acc[r][j + 1] + biasv[j + 1]);
                    *(__half2*)(cp + j) = p;
                }
            }
        }
    } else {
        float cs[TN];
#pragma unroll
        for (int j = 0; j < TN; ++j) cs[j] = 0.f;
#pragma unroll
        for (int r = 0; r < 4; ++r) {
            int gr = m0 + tr + r;
            if (gr < M) {
#pragma unroll
                for (int j = 0; j < TN; ++j) cs[j] += tanhf(acc[r][j] + biasv[j]);
            }
        }
        float* red = &As[0][0];
#pragma unroll
        for (int j = 0; j < TN; ++j) red[(tid >> 4) * BN + tc + j] = cs[j];
        __syncthreads();
        if (tid < BN) {
            float s = 0.f;
            for (int t16 = 0; t16 < 16; ++t16) s += red[t16 * BN + tid];
            unsafeAtomicAdd(&C[n0 + tid], s);
        }
    }
}

// ---------------- CSR build (count-free: histogram derived from binning) ----------
__global__ __launch_bounds__(256)
void init_bincur(int* __restrict__ binCur)
{
    int i = blockIdx.x * 256 + threadIdx.x;
    if (i < 10 * NBUCK) binCur[i] = (i % NBUCK) * CAPREG;
}

__global__ __launch_bounds__(256)
void csr_binA(const int* __restrict__ edges, int* __restrict__ binCur,
              unsigned* __restrict__ binned)
{
    __shared__ int lcnt[NBUCK];
    __shared__ int gbase[NBUCK];
    int rel = blockIdx.x / BPR;
    int blk = blockIdx.x - rel * BPR;
    int base = blk * EPB;
    int tid = threadIdx.x;
    for (int b = tid; b < NBUCK; b += 256) lcnt[b] = 0;
    __syncthreads();
    const int* er = edges + (long)rel * 2 * NE;
    const int* ec = er + NE;
    unsigned pk[16];
    unsigned mt[16];
#pragma unroll
    for (int k = 0; k < 16; ++k) {
        int i = base + k * 256 + tid;
        if (i < NE) {
            int r = er[i];
            int c = ec[i];
            int b = c >> 9;
            int lo = atomicAdd(&lcnt[b], 1);
            pk[k] = ((unsigned)c << 15) | (unsigned)r;
            mt[k] = ((unsigned)b << 16) | (unsigned)lo;
        } else {
            mt[k] = 0xFFFFFFFFu;
        }
    }
    __syncthreads();
    if (tid < NBUCK) gbase[tid] = atomicAdd(&binCur[rel * NBUCK + tid], lcnt[tid]);
    __syncthreads();
    unsigned* bn = binned + (long)rel * NBUCK * CAPREG;
#pragma unroll
    for (int k = 0; k < 16; ++k) {
        if (mt[k] != 0xFFFFFFFFu) {
            int b = mt[k] >> 16;
            int lo = mt[k] & 0xFFFF;
            bn[gbase[b] + lo] = pk[k];
        }
    }
}

__global__ __launch_bounds__(64)
void bucket_scan(const int* __restrict__ binCur, int* __restrict__ bbase,
                 int* __restrict__ off_all)
{
    int rel = blockIdx.x;
    int t = threadIdx.x;
    __shared__ int c[64];
    int v = (t < NBUCK) ? (binCur[rel * NBUCK + t] - t * CAPREG) : 0;
    c[t] = v;
    __syncthreads();
    for (int d = 1; d < 64; d <<= 1) {
        int u = (t >= d) ? c[t - d] : 0;
        __syncthreads();
        c[t] += u;
        __syncthreads();
    }
    if (t < NBUCK) bbase[rel * NBUCK + t] = c[t] - v;
    if (t == 0) off_all[rel * (NN + 1) + NN] = NE;
}

// Pass B: emits PACKED (col<<15)|row words into csr_row (cols are free here and
// needed by the edge-weight kernels).
__global__ __launch_bounds__(256)
void csr_binB(const int* __restrict__ binCur, const int* __restrict__ bbase,
              const unsigned* __restrict__ binned,
              int* __restrict__ off_all, unsigned* __restrict__ rows)
{
    __shared__ int cntS[512];
    __shared__ int lcur[512];
    __shared__ int part[256];
    __shared__ unsigned buf[BCAP];
    int rel = blockIdx.x / NBUCK;
    int bkt = blockIdx.x - rel * NBUCK;
    const unsigned* bn = binned + ((long)rel * NBUCK + bkt) * CAPREG;
    int* off = off_all + rel * (NN + 1);
    unsigned* rw = rows + (long)rel * NE;
    int cnt = binCur[rel * NBUCK + bkt] - bkt * CAPREG;
    int gbase = bbase[rel * NBUCK + bkt];
    int nb0 = bkt << 9;
    int nb1 = min(nb0 + 512, NN);
    int nloc = nb1 - nb0;
    int tid = threadIdx.x;

    cntS[tid] = 0; cntS[tid + 256] = 0;
    __syncthreads();
    for (int j = tid; j < cnt; j += 256) {
        int c = (int)(bn[j] >> 15);
        atomicAdd(&cntS[c - nb0], 1);
    }
    __syncthreads();
    int c0 = cntS[2 * tid], c1 = cntS[2 * tid + 1];
    part[tid] = c0 + c1;
    __syncthreads();
    for (int d = 1; d < 256; d <<= 1) {
        int u = (tid >= d) ? part[tid - d] : 0;
        __syncthreads();
        part[tid] += u;
        __syncthreads();
    }
    int pre = (tid == 0) ? 0 : part[tid - 1];
    cntS[2 * tid] = pre;
    cntS[2 * tid + 1] = pre + c0;
    __syncthreads();
    for (int i = tid; i < nloc; i += 256) off[nb0 + i] = gbase + cntS[i];
    lcur[tid] = cntS[tid]; lcur[tid + 256] = cntS[tid + 256];
    __syncthreads();
    if (cnt <= BCAP) {
        for (int j = tid; j < cnt; j += 256) {
            unsigned p = bn[j];
            int c = (int)(p >> 15);
            int pos = atomicAdd(&lcur[c - nb0], 1);
            buf[pos] = p;
        }
        __syncthreads();
        for (int i = tid; i < cnt; i += 256) rw[gbase + i] = buf[i];
    } else {
        for (int j = tid; j < cnt; j += 256) {
            unsigned p = bn[j];
            int c = (int)(p >> 15);
            int pos = atomicAdd(&lcur[c - nb0], 1);
            rw[gbase + pos] = p;
        }
    }
}

// ---------------- layer-1 attention dots (h1 in fp16) ----------------
__global__ __launch_bounds__(256)
void attn_dots1(const __half* __restrict__ h1h,
                const float* __restrict__ att_src,
                const float* __restrict__ att_dst,
                float* __restrict__ asrc, float* __restrict__ adst)
{
    int gid = blockIdx.x * 256 + threadIdx.x;
    int wave = gid >> 6;
    int lane = gid & 63;
    if (wave >= 4 * NN) return;
    int t = wave / NN;
    int n = wave - t * NN;
    __half2 hh = *(const __half2*)&h1h[(long)(t * NN + n) * 128 + 2 * lane];
    float2 hv = __half22float2(hh);
    const int SRCc[10] = {0,1,2,3,0,1,2,1,3,1};
    const int DSTc[10] = {0,1,2,3,1,0,1,2,1,3};
#pragma unroll
    for (int e = 0; e < 10; ++e) {
        if (SRCc[e] == t) {
            float2 av = *(const float2*)&att_src[e * 128 + 2 * lane];
            float p = hv.x * av.x + hv.y * av.y;
#pragma unroll
            for (int off = 1; off < 8; off <<= 1) p += __shfl_xor(p, off, 64);
            if ((lane & 7) == 0) asrc[(long)(e * NN + n) * 8 + (lane >> 3)] = p;
        }
        if (DSTc[e] == t) {
            float2 bv = *(const float2*)&att_dst[e * 128 + 2 * lane];
            float p = hv.x * bv.x + hv.y * bv.y;
#pragma unroll
            for (int off = 1; off < 8; off <<= 1) p += __shfl_xor(p, off, 64);
            if ((lane & 7) == 0) adst[(long)(e * NN + n) * 8 + (lane >> 3)] = p;
        }
    }
}

// ---------------- layer-1 per-edge softmax weights: one thread per (slot, head) ----
// w1h[j*8+h] = exp(leakyrelu(asrc[r,h] + adst[c,h])), fp16, coalesced.
__global__ __launch_bounds__(256)
void edge_w1(const unsigned* __restrict__ packed,
             const float* __restrict__ asrc_e, const float* __restrict__ adst_e,
             __half* __restrict__ w1h)
{
    int idx = blockIdx.x * 256 + threadIdx.x;
    if (idx >= NE * 8) return;
    int j = idx >> 3;
    int h = idx & 7;
    unsigned p = packed[j];
    int r = (int)(p & 0x7FFF);
    int c = (int)(p >> 15);
    float a = asrc_e[r * 8 + h] + adst_e[c * 8 + h];
    a = a > 0.f ? a : 0.2f * a;
    w1h[idx] = __float2half(__expf(a));
}

// ---------------- layer-1 gather-aggregate: precomputed weights, fp16 source -------
__global__ __launch_bounds__(256)
void gather_agg1(const int* __restrict__ off, const unsigned* __restrict__ rows,
                 const __half* __restrict__ w1h,
                 const __half* __restrict__ h1s, float* __restrict__ slot)
{
    int node = blockIdx.x * 4 + (threadIdx.x >> 6);
    int lane = threadIdx.x & 63;
    if (node >= NN) return;
    int h = lane >> 3;
    int beg = off[node], end = off[node + 1];
    float den = 1e-16f;
    float accx = 0.f, accy = 0.f;
    int j = beg;
    for (; j + 3 < end; j += 4) {
        unsigned p0 = rows[j];
        unsigned p1 = rows[j + 1];
        unsigned p2 = rows[j + 2];
        unsigned p3 = rows[j + 3];
        float w0 = __half2float(w1h[8 * j + h]);
        float w1 = __half2float(w1h[8 * (j + 1) + h]);
        float w2 = __half2float(w1h[8 * (j + 2) + h]);
        float w3 = __half2float(w1h[8 * (j + 3) + h]);
        int r0 = (int)(p0 & 0x7FFF);
        int r1 = (int)(p1 & 0x7FFF);
        int r2 = (int)(p2 & 0x7FFF);
        int r3 = (int)(p3 & 0x7FFF);
        float2 v0 = __half22float2(*(const __half2*)&h1s[(long)r0 * 128 + 2 * lane]);
        float2 v1 = __half22float2(*(const __half2*)&h1s[(long)r1 * 128 + 2 * lane]);
        float2 v2 = __half22float2(*(const __half2*)&h1s[(long)r2 * 128 + 2 * lane]);
        float2 v3 = __half22float2(*(const __half2*)&h1s[(long)r3 * 128 + 2 * lane]);
        den += (w0 + w1) + (w2 + w3);
        accx += w0 * v0.x + w1 * v1.x + w2 * v2.x + w3 * v3.x;
        accy += w0 * v0.y + w1 * v1.y + w2 * v2.y + w3 * v3.y;
    }
    for (; j < end; ++j) {
        unsigned p0 = rows[j];
        float w0 = __half2float(w1h[8 * j + h]);
        int r0 = (int)(p0 & 0x7FFF);
        float2 v0 = __half22float2(*(const __half2*)&h1s[(long)r0 * 128 + 2 * lane]);
        den += w0;
        accx += w0 * v0.x;
        accy += w0 * v0.y;
    }
    float inv = 1.0f / den;
    float2 o = {accx * inv, accy * inv};
    *(float2*)&slot[(long)node * 128 + 2 * lane] = o;
}

// ---------------- semantic score softmax for ONE dst type ----------------
__global__ void score_t_k(const float* __restrict__ colsum, const float* __restrict__ q,
                          float* __restrict__ sattn, int C, int t)
{
    __shared__ float sc[10];
    int tid = threadIdx.x;
    if (tid < 10) {
        if (d_DST[tid] == t) {
            float s = 0.f;
            for (int c = 0; c < C; ++c) s += q[c] * colsum[tid * C + c];
            sc[tid] = s / (float)NN;
        } else {
            sc[tid] = -1e30f;
        }
    }
    __syncthreads();
    if (tid == 0) {
        float mx = -1e30f;
        for (int m = 0; m < 10; ++m) if (d_DST[m] == t) mx = fmaxf(mx, sc[m]);
        float sum = 0.f;
        float ex[10];
        for (int m = 0; m < 10; ++m) {
            ex[m] = 0.f;
            if (d_DST[m] == t) { ex[m] = __expf(sc[m] - mx); sum += ex[m]; }
        }
        for (int m = 0; m < 10; ++m) if (d_DST[m] == t) sattn[m] = ex[m] / sum;
    }
}

// ---------------- per-type fusion: out = elu( sum_j sattn[r_j]*relu(slot_j) ) ---------
__global__ __launch_bounds__(256)
void fusion_t(const float* s0, const float* s1, const float* s2, const float* s3,
              int cnt, int r0, int r1, int r2, int r3,
              const float* __restrict__ sattn, float* __restrict__ out)
{
    int idx = blockIdx.x * 256 + threadIdx.x;
    if (idx >= NN * 32) return;
    int c4 = idx & 31;
    int n = idx >> 5;
    long off = (long)n * 128 + c4 * 4;
    const float* sl[4] = {s0, s1, s2, s3};
    int rl[4] = {r0, r1, r2, r3};
    float4 o = {0.f, 0.f, 0.f, 0.f};
    for (int j = 0; j < cnt; ++j) {
        float w = sattn[rl[j]];
        float4 v = *(const float4*)(sl[j] + off);
        o.x += w * fmaxf(v.x, 0.f);
        o.y += w * fmaxf(v.y, 0.f);
        o.z += w * fmaxf(v.z, 0.f);
        o.w += w * fmaxf(v.w, 0.f);
    }
    o.x = o.x > 0.f ? o.x : __expf(o.x) - 1.f;
    o.y = o.y > 0.f ? o.y : __expf(o.y) - 1.f;
    o.z = o.z > 0.f ? o.z : __expf(o.z) - 1.f;
    o.w = o.w > 0.f ? o.w : __expf(o.w) - 1.f;
    *(float4*)(out + off) = o;
}

// ---------------- layer-2 attention dots (h2 in fp16; 1 head, 32 ch) --------------
__global__ __launch_bounds__(256)
void attn_dots2(const __half* __restrict__ h2h,
                const float* __restrict__ att_src,
                const float* __restrict__ att_dst,
                float* __restrict__ asrc, float* __restrict__ adst)
{
    int gid = blockIdx.x * 256 + threadIdx.x;
    int p = gid >> 5;
    int l = gid & 31;
    if (p >= 10 * NN) return;
    int e = p / NN, n = p - e * NN;
    int s = d_SRC[e], d = d_DST[e];
    float hs = __half2float(h2h[(long)(s * NN + n) * 32 + l]);
    float hd = __half2float(h2h[(long)(d * NN + n) * 32 + l]);
    float ps = hs * att_src[e * 32 + l];
    float pd = hd * att_dst[e * 32 + l];
#pragma unroll
    for (int off = 1; off < 32; off <<= 1) {
        ps += __shfl_xor(ps, off, 64);
        pd += __shfl_xor(pd, off, 64);
    }
    if (l == 0) { asrc[e * NN + n] = ps; adst[e * NN + n] = pd; }
}

// ---------------- layer-2 per-edge weights: one thread per slot, all rels ---------
__global__ __launch_bounds__(256)
void edge_w2(const unsigned* __restrict__ packed_all,
             const float* __restrict__ asrc, const float* __restrict__ adst,
             float* __restrict__ wgt)
{
    int idx = blockIdx.x * 256 + threadIdx.x;
    if (idx >= 10 * NE) return;
    int rel = idx / NE;
    int j = idx - rel * NE;
    unsigned p = packed_all[(long)rel * NE + j];
    int r = (int)(p & 0x7FFF);
    int c = (int)(p >> 15);
    float a = asrc[rel * NN + r] + adst[rel * NN + c];
    a = a > 0.f ? a : 0.2f * a;
    wgt[idx] = __expf(a);
}

// ---------------- layer-2 gather-aggregate: precomputed weights, fp16 source -------
__global__ __launch_bounds__(256)
void gather_agg2(const int* __restrict__ csr_off, const unsigned* __restrict__ csr_rows,
                 const __half* __restrict__ h2h, const float* __restrict__ wgt,
                 float* __restrict__ agg2)
{
    int e = d_RORD[blockIdx.y];
    int node = blockIdx.x * 8 + (threadIdx.x >> 5);
    int lane = threadIdx.x & 31;
    if (node >= NN) return;
    const int* off = csr_off + e * (NN + 1);
    const unsigned* rows = csr_rows + (long)e * NE;
    const float* we = wgt + (long)e * NE;
    const __half* h2s = h2h + (long)d_SRC[e] * NN * 32;
    int beg = off[node], end = off[node + 1];
    float den = 1e-16f;
    float acc = 0.f;
    int j = beg;
    for (; j + 3 < end; j += 4) {
        unsigned p0 = rows[j];
        unsigned p1 = rows[j + 1];
        unsigned p2 = rows[j + 2];
        unsigned p3 = rows[j + 3];
        float w0 = we[j];
        float w1 = we[j + 1];
        float w2 = we[j + 2];
        float w3 = we[j + 3];
        int r0 = (int)(p0 & 0x7FFF);
        int r1 = (int)(p1 & 0x7FFF);
        int r2 = (int)(p2 & 0x7FFF);
        int r3 = (int)(p3 & 0x7FFF);
        float v0 = __half2float(h2s[(long)r0 * 32 + lane]);
        float v1 = __half2float(h2s[(long)r1 * 32 + lane]);
        float v2 = __half2float(h2s[(long)r2 * 32 + lane]);
        float v3 = __half2float(h2s[(long)r3 * 32 + lane]);
        den += (w0 + w1) + (w2 + w3);
        acc += w0 * v0 + w1 * v1 + w2 * v2 + w3 * v3;
    }
    for (; j < end; ++j) {
        unsigned p0 = rows[j];
        float w0 = we[j];
        int r0 = (int)(p0 & 0x7FFF);
        den += w0;
        acc += w0 * __half2float(h2s[(long)r0 * 32 + lane]);
    }
    agg2[((long)e * NN + node) * 32 + lane] = acc / den;
}

// ---------------- semantic score + softmax over ALL types (layer 2) ----------------
__global__ void score_all_k(const float* __restrict__ colsum, const float* __restrict__ q,
                            float* __restrict__ sattn, int C)
{
    __shared__ float sc[10];
    int tid = threadIdx.x;
    if (tid < 10) {
        float s = 0.f;
        for (int c = 0; c < C; ++c) s += q[c] * colsum[tid * C + c];
        sc[tid] = s / (float)NN;
    }
    __syncthreads();
    if (tid < 4) {
        float mx = -1e30f;
        for (int m = 0; m < 10; ++m) if (d_DST[m] == tid) mx = fmaxf(mx, sc[m]);
        float ex[10];
        float sum = 0.f;
        for (int m = 0; m < 10; ++m) {
            ex[m] = 0.f;
            if (d_DST[m] == tid) { ex[m] = __expf(sc[m] - mx); sum += ex[m]; }
        }
        for (int m = 0; m < 10; ++m) if (d_DST[m] == tid) sattn[m] = ex[m] / sum;
    }
}

// ---------------- final: per-node channel softmax, fp32 out ----------------
__global__ __launch_bounds__(256)
void final_softmax(const float* __restrict__ agg, const float* __restrict__ sattn,
                   float* __restrict__ out)
{
    int gid = blockIdx.x * 256 + threadIdx.x;
    int c = gid & 31;
    int p = gid >> 5;
    if (p >= 4 * NN) return;
    int t = p / NN, n = p - t * NN;
    float f = 0.f;
    for (int m = 0; m < 10; ++m) {
        if (d_DST[m] != t) continue;
        f += sattn[m] * fmaxf(agg[(long)(m * NN + n) * 32 + c], 0.f);
    }
    float mx = f;
#pragma unroll
    for (int off = 1; off < 32; off <<= 1) mx = fmaxf(mx, __shfl_xor(mx, off, 64));
    float ex = __expf(f - mx);
    float sm = ex;
#pragma unroll
    for (int off = 1; off < 32; off <<= 1) sm += __shfl_xor(sm, off, 64);
    out[(long)(t * NN + n) * 32 + c] = ex / sm;
}

extern "C" void kernel_launch(void* const* d_in, const int* in_sizes, int n_in,
                              void* d_out, int out_size, void* d_ws, size_t ws_size,
                              hipStream_t stream) {
    const float* x[4] = {
        (const float*)d_in[0], (const float*)d_in[1],
        (const float*)d_in[2], (const float*)d_in[3]};
    const int* edges = (const int*)d_in[4];
    const float* W1    = (const float*)d_in[5];
    const float* b1    = (const float*)d_in[6];
    const float* att1s = (const float*)d_in[7];
    const float* att1d = (const float*)d_in[8];
    const float* k1W   = (const float*)d_in[9];
    const float* k1b   = (const float*)d_in[10];
    const float* q1    = (const float*)d_in[11];
    const float* W2    = (const float*)d_in[12];
    const float* b2    = (const float*)d_in[13];
    const float* att2s = (const float*)d_in[14];
    const float* att2d = (const float*)d_in[15];
    const float* k2W   = (const float*)d_in[16];
    const float* k2b   = (const float*)d_in[17];
    const float* q2    = (const float*)d_in[18];

    // ---- workspace layout (floats), peak ~175 MB ----
    float* W = (float*)d_ws;
    // region 0 (15,360,000 floats):
    //   layer 1: h1h fp16 [0 .. 7.68M), w1buf fp16 per-rel weights [7.68M .. 9.28M)
    //   layer 2 overlay: h2h, agg2, asrc2, adst2
    __half* h1h    = (__half*)W;
    __half* w1buf  = (__half*)(W + 7680000);   // NE*8 halves = 1.6M float-slots
    float* slots   = W + 15360000;           // 5 x 3,840,000 = 19,200,000
    float* asrc1   = W + 34560000;           //  2,400,000
    float* adst1   = W + 36960000;           //  2,400,000
    float* colsum1 = W + 39360000;           //      1,280
    float* sattn1  = W + 39361280;           //         16
    float* colsum2 = W + 39361296;           //        320
    float* sattn2  = W + 39361616;           //         16
    int*   csr_off = (int*)(W + 39361640);   //    300,010 ints
    unsigned* csr_row = (unsigned*)(csr_off + 300016); // 4,000,000 u32 (packed col|row)
    // CSR-build scratch overlays the slots region (dead until gather_agg1):
    unsigned* binned = (unsigned*)(W + 15360000); // 10*59*12288 = 7,249,920 u32
    int*   binCur  = (int*)(W + 15360000 + 7249920); // 590 ints (bucket cursors)
    int*   bbase   = binCur + 640;                   // 590 ints (bucket CSR bases)
    // layer-2 overlay into region 0 (h1h/w1buf dead after layer-1 gathers):
    __half* h2h    = (__half*)W;             //  3,840,000 halves = 1,920,000 float-slots
    float* agg2    = W + 3840000;            //  9,600,000
    float* asrc2   = W + 13440000;           //    300,000
    float* adst2   = W + 13740000;           //    300,000
    // layer-2 edge weights overlay the slots region (dead after proj2 GEMMs):
    float* w2buf   = slots;                  //  4,000,000 floats

    const long SLOT = 3840000;  // NN*128
    auto slot_p = [&](int i) { return slots + (long)i * SLOT; };

    // ---- CSR build (count-free; offsets derived inside buckets) ----
    init_bincur<<<3, 256, 0, stream>>>(binCur);
    csr_binA<<<BPR * 10, 256, 0, stream>>>(edges, binCur, binned);
    bucket_scan<<<10, 64, 0, stream>>>(binCur, bbase, csr_off);
    csr_binB<<<NBUCK * 10, 256, 0, stream>>>(binCur, bbase, binned, csr_off, csr_row);

    hipMemsetAsync(colsum1, 0, 1632L * 4, stream);

    // layer-1 projection: h1h[t] = fp16( x[t] @ W1[t] + b1[t] )
    for (int t = 0; t < 4; ++t) {
        gemm_k<64><<<dim3(469, 2, 1), 256, 0, stream>>>(
            x[t], 0, W1 + (long)t * 256 * 128, 0, b1 + t * 128, 0,
            (float*)(h1h + (long)t * NN * 128), 0, NN, 256, 128, 0, 2);
    }

    attn_dots1<<<30000, 256, 0, stream>>>(h1h, att1s, att1d, asrc1, adst1);

    // per-dst-type schedule
    const int SRC[10] = {0,1,2,3,0,1,2,1,3,1};
    struct TypePlan { int t; int cnt; int rels[4]; int sl[4]; int outsl; };
    const TypePlan plan[4] = {
        {1, 4, {1,4,6,8}, {0,1,2,3}, 3},   // h1f[1] = slot3
        {2, 2, {2,7,0,0}, {0,1,0,0}, 1},   // h1f[2] = slot1
        {0, 2, {0,5,0,0}, {0,2,0,0}, 2},   // h1f[0] = slot2
        {3, 2, {3,9,0,0}, {0,4,0,0}, 4},   // h1f[3] = slot4
    };
    float* h1f[4];

    for (int p = 0; p < 4; ++p) {
        const TypePlan& tp = plan[p];
        for (int j = 0; j < tp.cnt; ++j) {
            int e = tp.rels[j];
            edge_w1<<<12500, 256, 0, stream>>>(
                csr_row + (long)e * NE,
                asrc1 + (long)e * NN * 8, adst1 + (long)e * NN * 8, w1buf);
            gather_agg1<<<7500, 256, 0, stream>>>(
                csr_off + e * (NN + 1), csr_row + (long)e * NE, w1buf,
                h1h + (long)SRC[e] * NN * 128, slot_p(tp.sl[j]));
        }
        for (int j = 0; j < tp.cnt; ++j) {
            int e = tp.rels[j];
            gemm_k<64><<<dim3(469, 2, 1), 256, 0, stream>>>(
                slot_p(tp.sl[j]), 0, k1W, 0, k1b, 0,
                colsum1 + (long)e * 128, 0, NN, 128, 128, 1, 1);
        }
        score_t_k<<<1, 32, 0, stream>>>(colsum1, q1, sattn1, 128, tp.t);
        fusion_t<<<3750, 256, 0, stream>>>(
            slot_p(tp.sl[0]), slot_p(tp.sl[1]),
            slot_p(tp.sl[tp.cnt > 2 ? 2 : 0]), slot_p(tp.sl[tp.cnt > 3 ? 3 : 0]),
            tp.cnt, tp.rels[0], tp.rels[1], tp.rels[2], tp.rels[3],
            sattn1, slot_p(tp.outsl));
        h1f[tp.t] = slot_p(tp.outsl);
    }

    // ---- layer 2 (region 0 layer-1 contents dead now; overlay) ----
    for (int t = 0; t < 4; ++t) {
        gemm_k<32><<<dim3(469, 1, 1), 256, 0, stream>>>(
            h1f[t], 0, W2 + (long)t * 128 * 32, 0, b2 + t * 32, 0,
            (float*)(h2h + (long)t * NN * 32), 0, NN, 128, 32, 0, 2);
    }

    attn_dots2<<<37500, 256, 0, stream>>>(h2h, att2s, att2d, asrc2, adst2);
    edge_w2<<<15625, 256, 0, stream>>>(csr_row, asrc2, adst2, w2buf);
    gather_agg2<<<dim3(3750, 10), 256, 0, stream>>>(
        csr_off, csr_row, h2h, w2buf, agg2);

    gemm_k<32><<<dim3(469, 1, 10), 256, 0, stream>>>(
        agg2, 960000L, k2W, 0, k2b, 0, colsum2, 32L, NN, 32, 32, 1, 1);
    score_all_k<<<1, 64, 0, stream>>>(colsum2, q2, sattn2, 32);
    final_softmax<<<15000, 256, 0, stream>>>(agg2, sattn2, (float*)d_out);
}

// Round 5
// 1082.162 us; speedup vs baseline: 1.1996x; 1.1996x over previous
//
#include <hip/hip_runtime.h>
#include <hip/hip_fp16.h>

#define NN 30000
#define NE 400000
#define NBUCK 59     // ceil(30000/512)
#define BPR 98       // blocks per relation in csr_binA: ceil(400000/4096)
#define EPB 4096     // edges per block in csr_binA
#define CAPREG 12288 // fixed slots per (rel,bucket) in binned scratch (mean 6827, sigma 82)
#define BCAP 12288   // LDS sort capacity in csr_binB

__constant__ int d_SRC[10] = {0,1,2,3,0,1,2,1,3,1};
__constant__ int d_DST[10] = {0,1,2,3,1,0,1,2,1,3};
// gather_agg2 relation order grouped by src type (L2 slice reuse): srcs 1,1,1,1,0,0,2,2,3,3
__constant__ int d_RORD[10] = {1,5,7,9,0,4,2,6,3,8};

typedef _Float16 f16x8 __attribute__((ext_vector_type(8)));
typedef float f32x4 __attribute__((ext_vector_type(4)));

// ---------------- MFMA GEMM: C[M,N] = act(A)[M,K] @ B[K,N] + bias ----
// A,B fp32 in HBM; converted to fp16 at LDS staging; fp32 MFMA accumulate.
// epi=0: store C fp32. epi=1: tanh + column-sum -> atomicAdd C[N]. epi=2: store fp16.
// BM=64 (4 waves x 16 rows), BK=32, BN in {64, 32} (4 or 2 16x16 frags per wave).
template<int BN>
__global__ __launch_bounds__(256)
void mgemm_k(const float* __restrict__ A, long sA,
             const float* __restrict__ B, long sB,
             const float* __restrict__ bias, long sBias,
             float* __restrict__ C, long sC,
             int M, int K, int N, int relu_a, int epi)
{
    constexpr int BM = 64, BK = 32;
    constexpr int NF = BN / 16;       // 16x16 frags per wave
    constexpr int LDK = BK + 8;       // padded LDS leading dim (halves): 80B rows -> 2-way (free)
    const int z = blockIdx.z;
    A += (long)z * sA;
    B += (long)z * sB;
    bias += (long)z * sBias;
    C += (long)z * sC;
    const int m0 = blockIdx.x * BM;
    const int n0 = blockIdx.y * BN;
    const int tid = threadIdx.x;
    const int wv = tid >> 6;
    const int l  = tid & 63;
    const int fm = l & 15;            // A-row / B-col / C-col within frag
    const int fg = l >> 4;            // k-group (x8) / C row-group (x4)

    __shared__ _Float16 As[BM][LDK];
    __shared__ _Float16 Bs[BN][LDK];
    __shared__ float red[4][BN];

    f32x4 acc[NF];
#pragma unroll
    for (int f = 0; f < NF; ++f) acc[f] = (f32x4){0.f, 0.f, 0.f, 0.f};

    const int arow = tid >> 2;          // 0..63
    const int akc  = (tid & 3) << 3;    // 0,8,16,24
    const int grow = m0 + arow;

    for (int k0 = 0; k0 < K; k0 += BK) {
        // ---- A stage: 8 fp32 -> 8 fp16, one b128 LDS write ----
        f16x8 ap;
        if (grow < M) {
            const float* aq = A + (long)grow * K + k0 + akc;
            float4 u0 = *(const float4*)aq;
            float4 u1 = *(const float4*)(aq + 4);
            float v[8] = {u0.x, u0.y, u0.z, u0.w, u1.x, u1.y, u1.z, u1.w};
            if (relu_a) {
#pragma unroll
                for (int j = 0; j < 8; ++j) v[j] = fmaxf(v[j], 0.f);
            }
#pragma unroll
            for (int j = 0; j < 8; ++j) ap[j] = (_Float16)v[j];
        } else {
#pragma unroll
            for (int j = 0; j < 8; ++j) ap[j] = (_Float16)0.f;
        }
        *(f16x8*)&As[arow][akc] = ap;

        // ---- B stage: transpose to Bs[n][k] (fp16) ----
        if constexpr (BN == 64) {
            const int bk = tid >> 4;            // 0..15, handles k = bk, bk+16
            const int bn = (tid & 15) << 2;
#pragma unroll
            for (int kk = 0; kk < 2; ++kk) {
                int kr = bk + kk * 16;
                float4 u = *(const float4*)(B + (long)(k0 + kr) * N + n0 + bn);
                Bs[bn + 0][kr] = (_Float16)u.x;
                Bs[bn + 1][kr] = (_Float16)u.y;
                Bs[bn + 2][kr] = (_Float16)u.z;
                Bs[bn + 3][kr] = (_Float16)u.w;
            }
        } else {                                 // BN == 32
            const int bk = tid >> 3;            // 0..31
            const int bn = (tid & 7) << 2;
            float4 u = *(const float4*)(B + (long)(k0 + bk) * N + n0 + bn);
            Bs[bn + 0][bk] = (_Float16)u.x;
            Bs[bn + 1][bk] = (_Float16)u.y;
            Bs[bn + 2][bk] = (_Float16)u.z;
            Bs[bn + 3][bk] = (_Float16)u.w;
        }
        __syncthreads();

        f16x8 a = *(const f16x8*)&As[wv * 16 + fm][fg * 8];
#pragma unroll
        for (int f = 0; f < NF; ++f) {
            f16x8 b = *(const f16x8*)&Bs[f * 16 + fm][fg * 8];
            acc[f] = __builtin_amdgcn_mfma_f32_16x16x32_f16(a, b, acc[f], 0, 0, 0);
        }
        __syncthreads();
    }

    // ---- epilogues (C/D layout: col = l&15, row = 4*(l>>4)+i) ----
    if (epi == 0) {
#pragma unroll
        for (int f = 0; f < NF; ++f) {
            float bz = bias[n0 + f * 16 + fm];
#pragma unroll
            for (int i = 0; i < 4; ++i) {
                int gr = m0 + wv * 16 + fg * 4 + i;
                if (gr < M) C[(long)gr * N + n0 + f * 16 + fm] = acc[f][i] + bz;
            }
        }
    } else if (epi == 2) {
        __half* Ch = (__half*)C;
#pragma unroll
        for (int f = 0; f < NF; ++f) {
            float bz = bias[n0 + f * 16 + fm];
#pragma unroll
            for (int i = 0; i < 4; ++i) {
                int gr = m0 + wv * 16 + fg * 4 + i;
                if (gr < M) Ch[(long)gr * N + n0 + f * 16 + fm] = __float2half(acc[f][i] + bz);
            }
        }
    } else {
#pragma unroll
        for (int f = 0; f < NF; ++f) {
            float bz = bias[n0 + f * 16 + fm];
            float s = 0.f;
#pragma unroll
            for (int i = 0; i < 4; ++i) {
                int gr = m0 + wv * 16 + fg * 4 + i;
                if (gr < M) s += tanhf(acc[f][i] + bz);
            }
            s += __shfl_xor(s, 16, 64);
            s += __shfl_xor(s, 32, 64);
            if (fg == 0) red[wv][f * 16 + fm] = s;
        }
        __syncthreads();
        if (tid < BN) {
            float s = red[0][tid] + red[1][tid] + red[2][tid] + red[3][tid];
            unsafeAtomicAdd(&C[n0 + tid], s);
        }
    }
}

// ---------------- CSR build (count-free: histogram derived from binning) ----------
__global__ __launch_bounds__(256)
void init_bincur(int* __restrict__ binCur)
{
    int i = blockIdx.x * 256 + threadIdx.x;
    if (i < 10 * NBUCK) binCur[i] = (i % NBUCK) * CAPREG;
}

__global__ __launch_bounds__(256)
void csr_binA(const int* __restrict__ edges, int* __restrict__ binCur,
              unsigned* __restrict__ binned)
{
    __shared__ int lcnt[NBUCK];
    __shared__ int gbase[NBUCK];
    int rel = blockIdx.x / BPR;
    int blk = blockIdx.x - rel * BPR;
    int base = blk * EPB;
    int tid = threadIdx.x;
    for (int b = tid; b < NBUCK; b += 256) lcnt[b] = 0;
    __syncthreads();
    const int* er = edges + (long)rel * 2 * NE;
    const int* ec = er + NE;
    unsigned pk[16];
    unsigned mt[16];
#pragma unroll
    for (int k = 0; k < 16; ++k) {
        int i = base + k * 256 + tid;
        if (i < NE) {
            int r = er[i];
            int c = ec[i];
            int b = c >> 9;
            int lo = atomicAdd(&lcnt[b], 1);
            pk[k] = ((unsigned)c << 15) | (unsigned)r;
            mt[k] = ((unsigned)b << 16) | (unsigned)lo;
        } else {
            mt[k] = 0xFFFFFFFFu;
        }
    }
    __syncthreads();
    if (tid < NBUCK) gbase[tid] = atomicAdd(&binCur[rel * NBUCK + tid], lcnt[tid]);
    __syncthreads();
    unsigned* bn = binned + (long)rel * NBUCK * CAPREG;
#pragma unroll
    for (int k = 0; k < 16; ++k) {
        if (mt[k] != 0xFFFFFFFFu) {
            int b = mt[k] >> 16;
            int lo = mt[k] & 0xFFFF;
            bn[gbase[b] + lo] = pk[k];
        }
    }
}

__global__ __launch_bounds__(64)
void bucket_scan(const int* __restrict__ binCur, int* __restrict__ bbase,
                 int* __restrict__ off_all)
{
    int rel = blockIdx.x;
    int t = threadIdx.x;
    __shared__ int c[64];
    int v = (t < NBUCK) ? (binCur[rel * NBUCK + t] - t * CAPREG) : 0;
    c[t] = v;
    __syncthreads();
    for (int d = 1; d < 64; d <<= 1) {
        int u = (t >= d) ? c[t - d] : 0;
        __syncthreads();
        c[t] += u;
        __syncthreads();
    }
    if (t < NBUCK) bbase[rel * NBUCK + t] = c[t] - v;
    if (t == 0) off_all[rel * (NN + 1) + NN] = NE;
}

__global__ __launch_bounds__(256)
void csr_binB(const int* __restrict__ binCur, const int* __restrict__ bbase,
              const unsigned* __restrict__ binned,
              int* __restrict__ off_all, int* __restrict__ rows)
{
    __shared__ int cntS[512];
    __shared__ int lcur[512];
    __shared__ int part[256];
    __shared__ int buf[BCAP];
    int rel = blockIdx.x / NBUCK;
    int bkt = blockIdx.x - rel * NBUCK;
    const unsigned* bn = binned + ((long)rel * NBUCK + bkt) * CAPREG;
    int* off = off_all + rel * (NN + 1);
    int* rw = rows + (long)rel * NE;
    int cnt = binCur[rel * NBUCK + bkt] - bkt * CAPREG;
    int gbase = bbase[rel * NBUCK + bkt];
    int nb0 = bkt << 9;
    int nb1 = min(nb0 + 512, NN);
    int nloc = nb1 - nb0;
    int tid = threadIdx.x;

    cntS[tid] = 0; cntS[tid + 256] = 0;
    __syncthreads();
    for (int j = tid; j < cnt; j += 256) {
        int c = (int)(bn[j] >> 15);
        atomicAdd(&cntS[c - nb0], 1);
    }
    __syncthreads();
    int c0 = cntS[2 * tid], c1 = cntS[2 * tid + 1];
    part[tid] = c0 + c1;
    __syncthreads();
    for (int d = 1; d < 256; d <<= 1) {
        int u = (tid >= d) ? part[tid - d] : 0;
        __syncthreads();
        part[tid] += u;
        __syncthreads();
    }
    int pre = (tid == 0) ? 0 : part[tid - 1];
    cntS[2 * tid] = pre;
    cntS[2 * tid + 1] = pre + c0;
    __syncthreads();
    for (int i = tid; i < nloc; i += 256) off[nb0 + i] = gbase + cntS[i];
    lcur[tid] = cntS[tid]; lcur[tid + 256] = cntS[tid + 256];
    __syncthreads();
    if (cnt <= BCAP) {
        for (int j = tid; j < cnt; j += 256) {
            unsigned p = bn[j];
            int r = (int)(p & 0x7FFF);
            int c = (int)(p >> 15);
            int pos = atomicAdd(&lcur[c - nb0], 1);
            buf[pos] = r;
        }
        __syncthreads();
        for (int i = tid; i < cnt; i += 256) rw[gbase + i] = buf[i];
    } else {
        for (int j = tid; j < cnt; j += 256) {
            unsigned p = bn[j];
            int r = (int)(p & 0x7FFF);
            int c = (int)(p >> 15);
            int pos = atomicAdd(&lcur[c - nb0], 1);
            rw[gbase + pos] = r;
        }
    }
}

// ---------------- layer-1 attention dots (h1 in fp16) ----------------
__global__ __launch_bounds__(256)
void attn_dots1(const __half* __restrict__ h1h,
                const float* __restrict__ att_src,
                const float* __restrict__ att_dst,
                float* __restrict__ asrc, float* __restrict__ adst)
{
    int gid = blockIdx.x * 256 + threadIdx.x;
    int wave = gid >> 6;
    int lane = gid & 63;
    if (wave >= 4 * NN) return;
    int t = wave / NN;
    int n = wave - t * NN;
    __half2 hh = *(const __half2*)&h1h[(long)(t * NN + n) * 128 + 2 * lane];
    float2 hv = __half22float2(hh);
    const int SRCc[10] = {0,1,2,3,0,1,2,1,3,1};
    const int DSTc[10] = {0,1,2,3,1,0,1,2,1,3};
#pragma unroll
    for (int e = 0; e < 10; ++e) {
        if (SRCc[e] == t) {
            float2 av = *(const float2*)&att_src[e * 128 + 2 * lane];
            float p = hv.x * av.x + hv.y * av.y;
#pragma unroll
            for (int off = 1; off < 8; off <<= 1) p += __shfl_xor(p, off, 64);
            if ((lane & 7) == 0) asrc[(long)(e * NN + n) * 8 + (lane >> 3)] = p;
        }
        if (DSTc[e] == t) {
            float2 bv = *(const float2*)&att_dst[e * 128 + 2 * lane];
            float p = hv.x * bv.x + hv.y * bv.y;
#pragma unroll
            for (int off = 1; off < 8; off <<= 1) p += __shfl_xor(p, off, 64);
            if ((lane & 7) == 0) adst[(long)(e * NN + n) * 8 + (lane >> 3)] = p;
        }
    }
}

// ---------------- layer-1 gather-aggregate: fp16 source, 4x unrolled ---------------
__global__ __launch_bounds__(256)
void gather_agg1(const int* __restrict__ off, const int* __restrict__ rows,
                 const float* __restrict__ asrc_e, const float* __restrict__ adst_e,
                 const __half* __restrict__ h1s, float* __restrict__ slot)
{
    int node = blockIdx.x * 4 + (threadIdx.x >> 6);
    int lane = threadIdx.x & 63;
    if (node >= NN) return;
    int h = lane >> 3;
    int beg = off[node], end = off[node + 1];
    float ad = adst_e[node * 8 + h];
    float den = 1e-16f;
    float accx = 0.f, accy = 0.f;
    int j = beg;
    for (; j + 3 < end; j += 4) {
        int r0 = rows[j];
        int r1 = rows[j + 1];
        int r2 = rows[j + 2];
        int r3 = rows[j + 3];
        float a0 = asrc_e[r0 * 8 + h] + ad;
        float a1 = asrc_e[r1 * 8 + h] + ad;
        float a2 = asrc_e[r2 * 8 + h] + ad;
        float a3 = asrc_e[r3 * 8 + h] + ad;
        __half2 q0 = *(const __half2*)&h1s[(long)r0 * 128 + 2 * lane];
        __half2 q1 = *(const __half2*)&h1s[(long)r1 * 128 + 2 * lane];
        __half2 q2 = *(const __half2*)&h1s[(long)r2 * 128 + 2 * lane];
        __half2 q3 = *(const __half2*)&h1s[(long)r3 * 128 + 2 * lane];
        a0 = a0 > 0.f ? a0 : 0.2f * a0;
        a1 = a1 > 0.f ? a1 : 0.2f * a1;
        a2 = a2 > 0.f ? a2 : 0.2f * a2;
        a3 = a3 > 0.f ? a3 : 0.2f * a3;
        float e0 = __expf(a0);
        float e1 = __expf(a1);
        float e2 = __expf(a2);
        float e3 = __expf(a3);
        float2 v0 = __half22float2(q0);
        float2 v1 = __half22float2(q1);
        float2 v2 = __half22float2(q2);
        float2 v3 = __half22float2(q3);
        den += (e0 + e1) + (e2 + e3);
        accx += e0 * v0.x + e1 * v1.x + e2 * v2.x + e3 * v3.x;
        accy += e0 * v0.y + e1 * v1.y + e2 * v2.y + e3 * v3.y;
    }
    for (; j < end; ++j) {
        int r0 = rows[j];
        float a0 = asrc_e[r0 * 8 + h] + ad;
        a0 = a0 > 0.f ? a0 : 0.2f * a0;
        float e0 = __expf(a0);
        float2 v0 = __half22float2(*(const __half2*)&h1s[(long)r0 * 128 + 2 * lane]);
        den += e0;
        accx += e0 * v0.x;
        accy += e0 * v0.y;
    }
    float inv = 1.0f / den;
    float2 o = {accx * inv, accy * inv};
    *(float2*)&slot[(long)node * 128 + 2 * lane] = o;
}

// ---------------- semantic score softmax for ONE dst type ----------------
__global__ void score_t_k(const float* __restrict__ colsum, const float* __restrict__ q,
                          float* __restrict__ sattn, int C, int t)
{
    __shared__ float sc[10];
    int tid = threadIdx.x;
    if (tid < 10) {
        if (d_DST[tid] == t) {
            float s = 0.f;
            for (int c = 0; c < C; ++c) s += q[c] * colsum[tid * C + c];
            sc[tid] = s / (float)NN;
        } else {
            sc[tid] = -1e30f;
        }
    }
    __syncthreads();
    if (tid == 0) {
        float mx = -1e30f;
        for (int m = 0; m < 10; ++m) if (d_DST[m] == t) mx = fmaxf(mx, sc[m]);
        float sum = 0.f;
        float ex[10];
        for (int m = 0; m < 10; ++m) {
            ex[m] = 0.f;
            if (d_DST[m] == t) { ex[m] = __expf(sc[m] - mx); sum += ex[m]; }
        }
        for (int m = 0; m < 10; ++m) if (d_DST[m] == t) sattn[m] = ex[m] / sum;
    }
}

// ---------------- per-type fusion: out = elu( sum_j sattn[r_j]*relu(slot_j) ) ---------
__global__ __launch_bounds__(256)
void fusion_t(const float* s0, const float* s1, const float* s2, const float* s3,
              int cnt, int r0, int r1, int r2, int r3,
              const float* __restrict__ sattn, float* __restrict__ out)
{
    int idx = blockIdx.x * 256 + threadIdx.x;
    if (idx >= NN * 32) return;
    int c4 = idx & 31;
    int n = idx >> 5;
    long off = (long)n * 128 + c4 * 4;
    const float* sl[4] = {s0, s1, s2, s3};
    int rl[4] = {r0, r1, r2, r3};
    float4 o = {0.f, 0.f, 0.f, 0.f};
    for (int j = 0; j < cnt; ++j) {
        float w = sattn[rl[j]];
        float4 v = *(const float4*)(sl[j] + off);
        o.x += w * fmaxf(v.x, 0.f);
        o.y += w * fmaxf(v.y, 0.f);
        o.z += w * fmaxf(v.z, 0.f);
        o.w += w * fmaxf(v.w, 0.f);
    }
    o.x = o.x > 0.f ? o.x : __expf(o.x) - 1.f;
    o.y = o.y > 0.f ? o.y : __expf(o.y) - 1.f;
    o.z = o.z > 0.f ? o.z : __expf(o.z) - 1.f;
    o.w = o.w > 0.f ? o.w : __expf(o.w) - 1.f;
    *(float4*)(out + off) = o;
}

// ---------------- layer-2 attention dots (h2 in fp16; 1 head, 32 ch) --------------
__global__ __launch_bounds__(256)
void attn_dots2(const __half* __restrict__ h2h,
                const float* __restrict__ att_src,
                const float* __restrict__ att_dst,
                float* __restrict__ asrc, float* __restrict__ adst)
{
    int gid = blockIdx.x * 256 + threadIdx.x;
    int p = gid >> 5;
    int l = gid & 31;
    if (p >= 10 * NN) return;
    int e = p / NN, n = p - e * NN;
    int s = d_SRC[e], d = d_DST[e];
    float hs = __half2float(h2h[(long)(s * NN + n) * 32 + l]);
    float hd = __half2float(h2h[(long)(d * NN + n) * 32 + l]);
    float ps = hs * att_src[e * 32 + l];
    float pd = hd * att_dst[e * 32 + l];
#pragma unroll
    for (int off = 1; off < 32; off <<= 1) {
        ps += __shfl_xor(ps, off, 64);
        pd += __shfl_xor(pd, off, 64);
    }
    if (l == 0) { asrc[e * NN + n] = ps; adst[e * NN + n] = pd; }
}

// ---------------- layer-2 gather-aggregate: fp16 source, 4x unrolled ---------------
__global__ __launch_bounds__(256)
void gather_agg2(const int* __restrict__ csr_off, const int* __restrict__ csr_rows,
                 const __half* __restrict__ h2h,
                 const float* __restrict__ asrc, const float* __restrict__ adst,
                 float* __restrict__ agg2)
{
    int e = d_RORD[blockIdx.y];
    int node = blockIdx.x * 8 + (threadIdx.x >> 5);
    int lane = threadIdx.x & 31;
    if (node >= NN) return;
    const int* off = csr_off + e * (NN + 1);
    const int* rows = csr_rows + (long)e * NE;
    const __half* h2s = h2h + (long)d_SRC[e] * NN * 32;
    const float* as = asrc + e * NN;
    float ad = adst[e * NN + node];
    int beg = off[node], end = off[node + 1];
    float den = 1e-16f;
    float acc = 0.f;
    int j = beg;
    for (; j + 3 < end; j += 4) {
        int r0 = rows[j];
        int r1 = rows[j + 1];
        int r2 = rows[j + 2];
        int r3 = rows[j + 3];
        float a0 = as[r0] + ad;
        float a1 = as[r1] + ad;
        float a2 = as[r2] + ad;
        float a3 = as[r3] + ad;
        __half q0 = h2s[(long)r0 * 32 + lane];
        __half q1 = h2s[(long)r1 * 32 + lane];
        __half q2 = h2s[(long)r2 * 32 + lane];
        __half q3 = h2s[(long)r3 * 32 + lane];
        a0 = a0 > 0.f ? a0 : 0.2f * a0;
        a1 = a1 > 0.f ? a1 : 0.2f * a1;
        a2 = a2 > 0.f ? a2 : 0.2f * a2;
        a3 = a3 > 0.f ? a3 : 0.2f * a3;
        float e0 = __expf(a0);
        float e1 = __expf(a1);
        float e2 = __expf(a2);
        float e3 = __expf(a3);
        den += (e0 + e1) + (e2 + e3);
        acc += e0 * __half2float(q0) + e1 * __half2float(q1)
             + e2 * __half2float(q2) + e3 * __half2float(q3);
    }
    for (; j < end; ++j) {
        int r0 = rows[j];
        float a0 = as[r0] + ad;
        a0 = a0 > 0.f ? a0 : 0.2f * a0;
        float e0 = __expf(a0);
        den += e0;
        acc += e0 * __half2float(h2s[(long)r0 * 32 + lane]);
    }
    agg2[((long)e * NN + node) * 32 + lane] = acc / den;
}

// ---------------- semantic score + softmax over ALL types (layer 2) ----------------
__global__ void score_all_k(const float* __restrict__ colsum, const float* __restrict__ q,
                            float* __restrict__ sattn, int C)
{
    __shared__ float sc[10];
    int tid = threadIdx.x;
    if (tid < 10) {
        float s = 0.f;
        for (int c = 0; c < C; ++c) s += q[c] * colsum[tid * C + c];
        sc[tid] = s / (float)NN;
    }
    __syncthreads();
    if (tid < 4) {
        float mx = -1e30f;
        for (int m = 0; m < 10; ++m) if (d_DST[m] == tid) mx = fmaxf(mx, sc[m]);
        float ex[10];
        float sum = 0.f;
        for (int m = 0; m < 10; ++m) {
            ex[m] = 0.f;
            if (d_DST[m] == tid) { ex[m] = __expf(sc[m] - mx); sum += ex[m]; }
        }
        for (int m = 0; m < 10; ++m) if (d_DST[m] == tid) sattn[m] = ex[m] / sum;
    }
}

// ---------------- final: per-node channel softmax, fp32 out ----------------
__global__ __launch_bounds__(256)
void final_softmax(const float* __restrict__ agg, const float* __restrict__ sattn,
                   float* __restrict__ out)
{
    int gid = blockIdx.x * 256 + threadIdx.x;
    int c = gid & 31;
    int p = gid >> 5;
    if (p >= 4 * NN) return;
    int t = p / NN, n = p - t * NN;
    float f = 0.f;
    for (int m = 0; m < 10; ++m) {
        if (d_DST[m] != t) continue;
        f += sattn[m] * fmaxf(agg[(long)(m * NN + n) * 32 + c], 0.f);
    }
    float mx = f;
#pragma unroll
    for (int off = 1; off < 32; off <<= 1) mx = fmaxf(mx, __shfl_xor(mx, off, 64));
    float ex = __expf(f - mx);
    float sm = ex;
#pragma unroll
    for (int off = 1; off < 32; off <<= 1) sm += __shfl_xor(sm, off, 64);
    out[(long)(t * NN + n) * 32 + c] = ex / sm;
}

extern "C" void kernel_launch(void* const* d_in, const int* in_sizes, int n_in,
                              void* d_out, int out_size, void* d_ws, size_t ws_size,
                              hipStream_t stream) {
    const float* x[4] = {
        (const float*)d_in[0], (const float*)d_in[1],
        (const float*)d_in[2], (const float*)d_in[3]};
    const int* edges = (const int*)d_in[4];
    const float* W1    = (const float*)d_in[5];
    const float* b1    = (const float*)d_in[6];
    const float* att1s = (const float*)d_in[7];
    const float* att1d = (const float*)d_in[8];
    const float* k1W   = (const float*)d_in[9];
    const float* k1b   = (const float*)d_in[10];
    const float* q1    = (const float*)d_in[11];
    const float* W2    = (const float*)d_in[12];
    const float* b2    = (const float*)d_in[13];
    const float* att2s = (const float*)d_in[14];
    const float* att2d = (const float*)d_in[15];
    const float* k2W   = (const float*)d_in[16];
    const float* k2b   = (const float*)d_in[17];
    const float* q2    = (const float*)d_in[18];

    // ---- workspace layout (floats), peak ~175 MB ----
    float* W = (float*)d_ws;
    // region 0 (15,360,000 floats): h1h fp16 during layer 1; layer-2 overlay after
    __half* h1h    = (__half*)W;
    float* slots   = W + 15360000;           // 5 x 3,840,000 = 19,200,000
    float* asrc1   = W + 34560000;           //  2,400,000
    float* adst1   = W + 36960000;           //  2,400,000
    float* colsum1 = W + 39360000;           //      1,280
    float* sattn1  = W + 39361280;           //         16
    float* colsum2 = W + 39361296;           //        320
    float* sattn2  = W + 39361616;           //         16
    int*   csr_off = (int*)(W + 39361640);   //    300,010 ints
    int*   csr_row = csr_off + 300016;       //  4,000,000 ints
    // CSR-build scratch overlays the slots region (dead until gather_agg1):
    unsigned* binned = (unsigned*)(W + 15360000); // 10*59*12288 = 7,249,920 u32
    int*   binCur  = (int*)(W + 15360000 + 7249920); // 590 ints (bucket cursors)
    int*   bbase   = binCur + 640;                   // 590 ints (bucket CSR bases)
    // layer-2 overlay into region 0 (h1h dead after layer-1 gathers):
    __half* h2h    = (__half*)W;             //  3,840,000 halves = 1,920,000 float-slots
    float* agg2    = W + 3840000;            //  9,600,000
    float* asrc2   = W + 13440000;           //    300,000
    float* adst2   = W + 13740000;           //    300,000

    const long SLOT = 3840000;  // NN*128
    auto slot_p = [&](int i) { return slots + (long)i * SLOT; };

    // ---- CSR build (count-free; offsets derived inside buckets) ----
    init_bincur<<<3, 256, 0, stream>>>(binCur);
    csr_binA<<<BPR * 10, 256, 0, stream>>>(edges, binCur, binned);
    bucket_scan<<<10, 64, 0, stream>>>(binCur, bbase, csr_off);
    csr_binB<<<NBUCK * 10, 256, 0, stream>>>(binCur, bbase, binned, csr_off, csr_row);

    hipMemsetAsync(colsum1, 0, 1632L * 4, stream);

    // layer-1 projection (MFMA): h1h[t] = fp16( x[t] @ W1[t] + b1[t] )
    for (int t = 0; t < 4; ++t) {
        mgemm_k<64><<<dim3(469, 2, 1), 256, 0, stream>>>(
            x[t], 0, W1 + (long)t * 256 * 128, 0, b1 + t * 128, 0,
            (float*)(h1h + (long)t * NN * 128), 0, NN, 256, 128, 0, 2);
    }

    attn_dots1<<<30000, 256, 0, stream>>>(h1h, att1s, att1d, asrc1, adst1);

    // per-dst-type schedule
    const int SRC[10] = {0,1,2,3,0,1,2,1,3,1};
    struct TypePlan { int t; int cnt; int rels[4]; int sl[4]; int outsl; };
    const TypePlan plan[4] = {
        {1, 4, {1,4,6,8}, {0,1,2,3}, 3},   // h1f[1] = slot3
        {2, 2, {2,7,0,0}, {0,1,0,0}, 1},   // h1f[2] = slot1
        {0, 2, {0,5,0,0}, {0,2,0,0}, 2},   // h1f[0] = slot2
        {3, 2, {3,9,0,0}, {0,4,0,0}, 4},   // h1f[3] = slot4
    };
    float* h1f[4];

    for (int p = 0; p < 4; ++p) {
        const TypePlan& tp = plan[p];
        for (int j = 0; j < tp.cnt; ++j) {
            int e = tp.rels[j];
            gather_agg1<<<7500, 256, 0, stream>>>(
                csr_off + e * (NN + 1), csr_row + (long)e * NE,
                asrc1 + (long)e * NN * 8, adst1 + (long)e * NN * 8,
                h1h + (long)SRC[e] * NN * 128, slot_p(tp.sl[j]));
        }
        for (int j = 0; j < tp.cnt; ++j) {
            int e = tp.rels[j];
            mgemm_k<64><<<dim3(469, 2, 1), 256, 0, stream>>>(
                slot_p(tp.sl[j]), 0, k1W, 0, k1b, 0,
                colsum1 + (long)e * 128, 0, NN, 128, 128, 1, 1);
        }
        score_t_k<<<1, 32, 0, stream>>>(colsum1, q1, sattn1, 128, tp.t);
        fusion_t<<<3750, 256, 0, stream>>>(
            slot_p(tp.sl[0]), slot_p(tp.sl[1]),
            slot_p(tp.sl[tp.cnt > 2 ? 2 : 0]), slot_p(tp.sl[tp.cnt > 3 ? 3 : 0]),
            tp.cnt, tp.rels[0], tp.rels[1], tp.rels[2], tp.rels[3],
            sattn1, slot_p(tp.outsl));
        h1f[tp.t] = slot_p(tp.outsl);
    }

    // ---- layer 2 (region 0 layer-1 contents dead now; overlay) ----
    for (int t = 0; t < 4; ++t) {
        mgemm_k<32><<<dim3(469, 1, 1), 256, 0, stream>>>(
            h1f[t], 0, W2 + (long)t * 128 * 32, 0, b2 + t * 32, 0,
            (float*)(h2h + (long)t * NN * 32), 0, NN, 128, 32, 0, 2);
    }

    attn_dots2<<<37500, 256, 0, stream>>>(h2h, att2s, att2d, asrc2, adst2);
    gather_agg2<<<dim3(3750, 10), 256, 0, stream>>>(
        csr_off, csr_row, h2h, asrc2, adst2, agg2);

    mgemm_k<32><<<dim3(469, 1, 10), 256, 0, stream>>>(
        agg2, 960000L, k2W, 0, k2b, 0, colsum2, 32L, NN, 32, 32, 1, 1);
    score_all_k<<<1, 64, 0, stream>>>(colsum2, q2, sattn2, 32);
    final_softmax<<<15000, 256, 0, stream>>>(agg2, sattn2, (float*)d_out);
}

// Round 6
// 1066.243 us; speedup vs baseline: 1.2175x; 1.0149x over previous
//
#include <hip/hip_runtime.h>
#include <hip/hip_fp16.h>

#define NN 30000
#define NE 400000
#define NBUCK 59     // ceil(30000/512)
#define BPR 98       // blocks per relation in csr_binA: ceil(400000/4096)
#define EPB 4096     // edges per block in csr_binA
#define CAPREG 12288 // fixed slots per (rel,bucket) in binned scratch (mean 6827, sigma 82)
#define BCAP 12288   // LDS sort capacity in csr_binB

__constant__ int d_SRC[10] = {0,1,2,3,0,1,2,1,3,1};
__constant__ int d_DST[10] = {0,1,2,3,1,0,1,2,1,3};
// gather_agg2 relation order grouped by src type (L2 slice reuse): srcs 1,1,1,1,0,0,2,2,3,3
__constant__ int d_RORD[10] = {1,5,7,9,0,4,2,6,3,8};

typedef _Float16 f16x8 __attribute__((ext_vector_type(8)));
typedef float f32x4 __attribute__((ext_vector_type(4)));

// ---------------- MFMA GEMM: C[M,N] = act(A)[M,K] @ B[K,N] + bias ----
// A,B fp32 in HBM; converted to fp16 at LDS staging; fp32 MFMA accumulate.
// epi=0: store C fp32. epi=1: tanh + column-sum -> atomicAdd C[N]. epi=2: store fp16.
// BM=64 (4 waves x 16 rows), BK=32, BN in {64, 32} (4 or 2 16x16 frags per wave).
template<int BN>
__global__ __launch_bounds__(256)
void mgemm_k(const float* __restrict__ A, long sA,
             const float* __restrict__ B, long sB,
             const float* __restrict__ bias, long sBias,
             float* __restrict__ C, long sC,
             int M, int K, int N, int relu_a, int epi)
{
    constexpr int BM = 64, BK = 32;
    constexpr int NF = BN / 16;       // 16x16 frags per wave
    constexpr int LDK = BK + 8;       // padded LDS leading dim (halves): 80B rows -> 2-way (free)
    const int z = blockIdx.z;
    A += (long)z * sA;
    B += (long)z * sB;
    bias += (long)z * sBias;
    C += (long)z * sC;
    const int m0 = blockIdx.x * BM;
    const int n0 = blockIdx.y * BN;
    const int tid = threadIdx.x;
    const int wv = tid >> 6;
    const int l  = tid & 63;
    const int fm = l & 15;            // A-row / B-col / C-col within frag
    const int fg = l >> 4;            // k-group (x8) / C row-group (x4)

    __shared__ _Float16 As[BM][LDK];
    __shared__ _Float16 Bs[BN][LDK];
    __shared__ float red[4][BN];

    f32x4 acc[NF];
#pragma unroll
    for (int f = 0; f < NF; ++f) acc[f] = (f32x4){0.f, 0.f, 0.f, 0.f};

    const int arow = tid >> 2;          // 0..63
    const int akc  = (tid & 3) << 3;    // 0,8,16,24
    const int grow = m0 + arow;

    for (int k0 = 0; k0 < K; k0 += BK) {
        // ---- A stage: 8 fp32 -> 8 fp16, one b128 LDS write ----
        f16x8 ap;
        if (grow < M) {
            const float* aq = A + (long)grow * K + k0 + akc;
            float4 u0 = *(const float4*)aq;
            float4 u1 = *(const float4*)(aq + 4);
            float v[8] = {u0.x, u0.y, u0.z, u0.w, u1.x, u1.y, u1.z, u1.w};
            if (relu_a) {
#pragma unroll
                for (int j = 0; j < 8; ++j) v[j] = fmaxf(v[j], 0.f);
            }
#pragma unroll
            for (int j = 0; j < 8; ++j) ap[j] = (_Float16)v[j];
        } else {
#pragma unroll
            for (int j = 0; j < 8; ++j) ap[j] = (_Float16)0.f;
        }
        *(f16x8*)&As[arow][akc] = ap;

        // ---- B stage: transpose to Bs[n][k] (fp16) ----
        if constexpr (BN == 64) {
            const int bk = tid >> 4;            // 0..15, handles k = bk, bk+16
            const int bn = (tid & 15) << 2;
#pragma unroll
            for (int kk = 0; kk < 2; ++kk) {
                int kr = bk + kk * 16;
                float4 u = *(const float4*)(B + (long)(k0 + kr) * N + n0 + bn);
                Bs[bn + 0][kr] = (_Float16)u.x;
                Bs[bn + 1][kr] = (_Float16)u.y;
                Bs[bn + 2][kr] = (_Float16)u.z;
                Bs[bn + 3][kr] = (_Float16)u.w;
            }
        } else {                                 // BN == 32
            const int bk = tid >> 3;            // 0..31
            const int bn = (tid & 7) << 2;
            float4 u = *(const float4*)(B + (long)(k0 + bk) * N + n0 + bn);
            Bs[bn + 0][bk] = (_Float16)u.x;
            Bs[bn + 1][bk] = (_Float16)u.y;
            Bs[bn + 2][bk] = (_Float16)u.z;
            Bs[bn + 3][bk] = (_Float16)u.w;
        }
        __syncthreads();

        f16x8 a = *(const f16x8*)&As[wv * 16 + fm][fg * 8];
#pragma unroll
        for (int f = 0; f < NF; ++f) {
            f16x8 b = *(const f16x8*)&Bs[f * 16 + fm][fg * 8];
            acc[f] = __builtin_amdgcn_mfma_f32_16x16x32_f16(a, b, acc[f], 0, 0, 0);
        }
        __syncthreads();
    }

    // ---- epilogues (C/D layout: col = l&15, row = 4*(l>>4)+i) ----
    if (epi == 0) {
#pragma unroll
        for (int f = 0; f < NF; ++f) {
            float bz = bias[n0 + f * 16 + fm];
#pragma unroll
            for (int i = 0; i < 4; ++i) {
                int gr = m0 + wv * 16 + fg * 4 + i;
                if (gr < M) C[(long)gr * N + n0 + f * 16 + fm] = acc[f][i] + bz;
            }
        }
    } else if (epi == 2) {
        __half* Ch = (__half*)C;
#pragma unroll
        for (int f = 0; f < NF; ++f) {
            float bz = bias[n0 + f * 16 + fm];
#pragma unroll
            for (int i = 0; i < 4; ++i) {
                int gr = m0 + wv * 16 + fg * 4 + i;
                if (gr < M) Ch[(long)gr * N + n0 + f * 16 + fm] = __float2half(acc[f][i] + bz);
            }
        }
    } else {
#pragma unroll
        for (int f = 0; f < NF; ++f) {
            float bz = bias[n0 + f * 16 + fm];
            float s = 0.f;
#pragma unroll
            for (int i = 0; i < 4; ++i) {
                int gr = m0 + wv * 16 + fg * 4 + i;
                if (gr < M) s += tanhf(acc[f][i] + bz);
            }
            s += __shfl_xor(s, 16, 64);
            s += __shfl_xor(s, 32, 64);
            if (fg == 0) red[wv][f * 16 + fm] = s;
        }
        __syncthreads();
        if (tid < BN) {
            float s = red[0][tid] + red[1][tid] + red[2][tid] + red[3][tid];
            unsafeAtomicAdd(&C[n0 + tid], s);
        }
    }
}

// ---------------- CSR build (count-free: histogram derived from binning) ----------
__global__ __launch_bounds__(256)
void init_bincur(int* __restrict__ binCur)
{
    int i = blockIdx.x * 256 + threadIdx.x;
    if (i < 10 * NBUCK) binCur[i] = (i % NBUCK) * CAPREG;
}

__global__ __launch_bounds__(256)
void csr_binA(const int* __restrict__ edges, int* __restrict__ binCur,
              unsigned* __restrict__ binned)
{
    __shared__ int lcnt[NBUCK];
    __shared__ int gbase[NBUCK];
    int rel = blockIdx.x / BPR;
    int blk = blockIdx.x - rel * BPR;
    int base = blk * EPB;
    int tid = threadIdx.x;
    for (int b = tid; b < NBUCK; b += 256) lcnt[b] = 0;
    __syncthreads();
    const int* er = edges + (long)rel * 2 * NE;
    const int* ec = er + NE;
    unsigned pk[16];
    unsigned mt[16];
#pragma unroll
    for (int k = 0; k < 16; ++k) {
        int i = base + k * 256 + tid;
        if (i < NE) {
            int r = er[i];
            int c = ec[i];
            int b = c >> 9;
            int lo = atomicAdd(&lcnt[b], 1);
            pk[k] = ((unsigned)c << 15) | (unsigned)r;
            mt[k] = ((unsigned)b << 16) | (unsigned)lo;
        } else {
            mt[k] = 0xFFFFFFFFu;
        }
    }
    __syncthreads();
    if (tid < NBUCK) gbase[tid] = atomicAdd(&binCur[rel * NBUCK + tid], lcnt[tid]);
    __syncthreads();
    unsigned* bn = binned + (long)rel * NBUCK * CAPREG;
#pragma unroll
    for (int k = 0; k < 16; ++k) {
        if (mt[k] != 0xFFFFFFFFu) {
            int b = mt[k] >> 16;
            int lo = mt[k] & 0xFFFF;
            bn[gbase[b] + lo] = pk[k];
        }
    }
}

__global__ __launch_bounds__(64)
void bucket_scan(const int* __restrict__ binCur, int* __restrict__ bbase,
                 int* __restrict__ off_all)
{
    int rel = blockIdx.x;
    int t = threadIdx.x;
    __shared__ int c[64];
    int v = (t < NBUCK) ? (binCur[rel * NBUCK + t] - t * CAPREG) : 0;
    c[t] = v;
    __syncthreads();
    for (int d = 1; d < 64; d <<= 1) {
        int u = (t >= d) ? c[t - d] : 0;
        __syncthreads();
        c[t] += u;
        __syncthreads();
    }
    if (t < NBUCK) bbase[rel * NBUCK + t] = c[t] - v;
    if (t == 0) off_all[rel * (NN + 1) + NN] = NE;
}

__global__ __launch_bounds__(256)
void csr_binB(const int* __restrict__ binCur, const int* __restrict__ bbase,
              const unsigned* __restrict__ binned,
              int* __restrict__ off_all, int* __restrict__ rows)
{
    __shared__ int cntS[512];
    __shared__ int lcur[512];
    __shared__ int part[256];
    __shared__ int buf[BCAP];
    int rel = blockIdx.x / NBUCK;
    int bkt = blockIdx.x - rel * NBUCK;
    const unsigned* bn = binned + ((long)rel * NBUCK + bkt) * CAPREG;
    int* off = off_all + rel * (NN + 1);
    int* rw = rows + (long)rel * NE;
    int cnt = binCur[rel * NBUCK + bkt] - bkt * CAPREG;
    int gbase = bbase[rel * NBUCK + bkt];
    int nb0 = bkt << 9;
    int nb1 = min(nb0 + 512, NN);
    int nloc = nb1 - nb0;
    int tid = threadIdx.x;

    cntS[tid] = 0; cntS[tid + 256] = 0;
    __syncthreads();
    for (int j = tid; j < cnt; j += 256) {
        int c = (int)(bn[j] >> 15);
        atomicAdd(&cntS[c - nb0], 1);
    }
    __syncthreads();
    int c0 = cntS[2 * tid], c1 = cntS[2 * tid + 1];
    part[tid] = c0 + c1;
    __syncthreads();
    for (int d = 1; d < 256; d <<= 1) {
        int u = (tid >= d) ? part[tid - d] : 0;
        __syncthreads();
        part[tid] += u;
        __syncthreads();
    }
    int pre = (tid == 0) ? 0 : part[tid - 1];
    cntS[2 * tid] = pre;
    cntS[2 * tid + 1] = pre + c0;
    __syncthreads();
    for (int i = tid; i < nloc; i += 256) off[nb0 + i] = gbase + cntS[i];
    lcur[tid] = cntS[tid]; lcur[tid + 256] = cntS[tid + 256];
    __syncthreads();
    if (cnt <= BCAP) {
        for (int j = tid; j < cnt; j += 256) {
            unsigned p = bn[j];
            int r = (int)(p & 0x7FFF);
            int c = (int)(p >> 15);
            int pos = atomicAdd(&lcur[c - nb0], 1);
            buf[pos] = r;
        }
        __syncthreads();
        for (int i = tid; i < cnt; i += 256) rw[gbase + i] = buf[i];
    } else {
        for (int j = tid; j < cnt; j += 256) {
            unsigned p = bn[j];
            int r = (int)(p & 0x7FFF);
            int c = (int)(p >> 15);
            int pos = atomicAdd(&lcur[c - nb0], 1);
            rw[gbase + pos] = r;
        }
    }
}

// ---------------- layer-1 attention dots (h1 in fp16) ----------------
__global__ __launch_bounds__(256)
void attn_dots1(const __half* __restrict__ h1h,
                const float* __restrict__ att_src,
                const float* __restrict__ att_dst,
                float* __restrict__ asrc, float* __restrict__ adst)
{
    int gid = blockIdx.x * 256 + threadIdx.x;
    int wave = gid >> 6;
    int lane = gid & 63;
    if (wave >= 4 * NN) return;
    int t = wave / NN;
    int n = wave - t * NN;
    __half2 hh = *(const __half2*)&h1h[(long)(t * NN + n) * 128 + 2 * lane];
    float2 hv = __half22float2(hh);
    const int SRCc[10] = {0,1,2,3,0,1,2,1,3,1};
    const int DSTc[10] = {0,1,2,3,1,0,1,2,1,3};
#pragma unroll
    for (int e = 0; e < 10; ++e) {
        if (SRCc[e] == t) {
            float2 av = *(const float2*)&att_src[e * 128 + 2 * lane];
            float p = hv.x * av.x + hv.y * av.y;
#pragma unroll
            for (int off = 1; off < 8; off <<= 1) p += __shfl_xor(p, off, 64);
            if ((lane & 7) == 0) asrc[(long)(e * NN + n) * 8 + (lane >> 3)] = p;
        }
        if (DSTc[e] == t) {
            float2 bv = *(const float2*)&att_dst[e * 128 + 2 * lane];
            float p = hv.x * bv.x + hv.y * bv.y;
#pragma unroll
            for (int off = 1; off < 8; off <<= 1) p += __shfl_xor(p, off, 64);
            if ((lane & 7) == 0) adst[(long)(e * NN + n) * 8 + (lane >> 3)] = p;
        }
    }
}

// ---------------- layer-1 gather-aggregate: in-wave two-phase rounds ----------------
// Round of 8 edges: phase A computes each (edge, head) weight EXACTLY ONCE
// (lane = edge(lane>>3) x head(lane&7)); phase B redistributes via shfl (LDS pipe)
// and does the fp16 value FMAs. Removes the 8x weight-math replication.
__global__ __launch_bounds__(256)
void gather_agg1(const int* __restrict__ off, const int* __restrict__ rows,
                 const float* __restrict__ asrc_e, const float* __restrict__ adst_e,
                 const __half* __restrict__ h1s, float* __restrict__ slot)
{
    int node = blockIdx.x * 4 + (threadIdx.x >> 6);
    int lane = threadIdx.x & 63;
    if (node >= NN) return;
    const int hB = lane >> 3;     // head owning this lane's 2 value channels
    const int hA = lane & 7;      // head this lane computes weights for (phase A)
    const int eA = lane >> 3;     // edge-in-round this lane computes weights for
    int beg = off[node], end = off[node + 1];
    float adA = adst_e[node * 8 + hA];
    float den = 1e-16f;
    float accx = 0.f, accy = 0.f;
    for (int j0 = beg; j0 < end; j0 += 8) {
        int jj = j0 + eA;
        bool ok = jj < end;
        int r = rows[ok ? jj : beg];
        float a = asrc_e[r * 8 + hA] + adA;
        a = a > 0.f ? a : 0.2f * a;
        float w = ok ? __expf(a) : 0.f;
        int cnt = end - j0;
        if (cnt >= 8) {
#pragma unroll
            for (int i = 0; i < 8; ++i) {
                float wi = __shfl(w, i * 8 + hB, 64);
                int ri = __shfl(r, i * 8, 64);
                float2 v = __half22float2(*(const __half2*)&h1s[(long)ri * 128 + 2 * lane]);
                den += wi;
                accx += wi * v.x;
                accy += wi * v.y;
            }
        } else {
            for (int i = 0; i < cnt; ++i) {
                float wi = __shfl(w, i * 8 + hB, 64);
                int ri = __shfl(r, i * 8, 64);
                float2 v = __half22float2(*(const __half2*)&h1s[(long)ri * 128 + 2 * lane]);
                den += wi;
                accx += wi * v.x;
                accy += wi * v.y;
            }
        }
    }
    float inv = 1.0f / den;
    float2 o = {accx * inv, accy * inv};
    *(float2*)&slot[(long)node * 128 + 2 * lane] = o;
}

// ---------------- semantic score softmax for ONE dst type ----------------
__global__ void score_t_k(const float* __restrict__ colsum, const float* __restrict__ q,
                          float* __restrict__ sattn, int C, int t)
{
    __shared__ float sc[10];
    int tid = threadIdx.x;
    if (tid < 10) {
        if (d_DST[tid] == t) {
            float s = 0.f;
            for (int c = 0; c < C; ++c) s += q[c] * colsum[tid * C + c];
            sc[tid] = s / (float)NN;
        } else {
            sc[tid] = -1e30f;
        }
    }
    __syncthreads();
    if (tid == 0) {
        float mx = -1e30f;
        for (int m = 0; m < 10; ++m) if (d_DST[m] == t) mx = fmaxf(mx, sc[m]);
        float sum = 0.f;
        float ex[10];
        for (int m = 0; m < 10; ++m) {
            ex[m] = 0.f;
            if (d_DST[m] == t) { ex[m] = __expf(sc[m] - mx); sum += ex[m]; }
        }
        for (int m = 0; m < 10; ++m) if (d_DST[m] == t) sattn[m] = ex[m] / sum;
    }
}

// ---------------- per-type fusion: out = elu( sum_j sattn[r_j]*relu(slot_j) ) ---------
__global__ __launch_bounds__(256)
void fusion_t(const float* s0, const float* s1, const float* s2, const float* s3,
              int cnt, int r0, int r1, int r2, int r3,
              const float* __restrict__ sattn, float* __restrict__ out)
{
    int idx = blockIdx.x * 256 + threadIdx.x;
    if (idx >= NN * 32) return;
    int c4 = idx & 31;
    int n = idx >> 5;
    long off = (long)n * 128 + c4 * 4;
    const float* sl[4] = {s0, s1, s2, s3};
    int rl[4] = {r0, r1, r2, r3};
    float4 o = {0.f, 0.f, 0.f, 0.f};
    for (int j = 0; j < cnt; ++j) {
        float w = sattn[rl[j]];
        float4 v = *(const float4*)(sl[j] + off);
        o.x += w * fmaxf(v.x, 0.f);
        o.y += w * fmaxf(v.y, 0.f);
        o.z += w * fmaxf(v.z, 0.f);
        o.w += w * fmaxf(v.w, 0.f);
    }
    o.x = o.x > 0.f ? o.x : __expf(o.x) - 1.f;
    o.y = o.y > 0.f ? o.y : __expf(o.y) - 1.f;
    o.z = o.z > 0.f ? o.z : __expf(o.z) - 1.f;
    o.w = o.w > 0.f ? o.w : __expf(o.w) - 1.f;
    *(float4*)(out + off) = o;
}

// ---------------- layer-2 attention dots (h2 in fp16; 1 head, 32 ch) --------------
__global__ __launch_bounds__(256)
void attn_dots2(const __half* __restrict__ h2h,
                const float* __restrict__ att_src,
                const float* __restrict__ att_dst,
                float* __restrict__ asrc, float* __restrict__ adst)
{
    int gid = blockIdx.x * 256 + threadIdx.x;
    int p = gid >> 5;
    int l = gid & 31;
    if (p >= 10 * NN) return;
    int e = p / NN, n = p - e * NN;
    int s = d_SRC[e], d = d_DST[e];
    float hs = __half2float(h2h[(long)(s * NN + n) * 32 + l]);
    float hd = __half2float(h2h[(long)(d * NN + n) * 32 + l]);
    float ps = hs * att_src[e * 32 + l];
    float pd = hd * att_dst[e * 32 + l];
#pragma unroll
    for (int off = 1; off < 32; off <<= 1) {
        ps += __shfl_xor(ps, off, 64);
        pd += __shfl_xor(pd, off, 64);
    }
    if (l == 0) { asrc[e * NN + n] = ps; adst[e * NN + n] = pd; }
}

// ---------------- layer-2 gather-aggregate: in-wave two-phase rounds --------------
// Round of 32 edges: phase A computes each edge weight once (edge = lane);
// phase B redistributes via width-32 shfl and does the value FMAs (4x unrolled).
__global__ __launch_bounds__(256)
void gather_agg2(const int* __restrict__ csr_off, const int* __restrict__ csr_rows,
                 const __half* __restrict__ h2h,
                 const float* __restrict__ asrc, const float* __restrict__ adst,
                 float* __restrict__ agg2)
{
    int e = d_RORD[blockIdx.y];
    int node = blockIdx.x * 8 + (threadIdx.x >> 5);
    int lane = threadIdx.x & 31;
    if (node >= NN) return;
    const int* off = csr_off + e * (NN + 1);
    const int* rows = csr_rows + (long)e * NE;
    const __half* h2s = h2h + (long)d_SRC[e] * NN * 32;
    const float* as = asrc + e * NN;
    float ad = adst[e * NN + node];
    int beg = off[node], end = off[node + 1];
    float den = 1e-16f;
    float acc = 0.f;
    for (int j0 = beg; j0 < end; j0 += 32) {
        int jj = j0 + lane;
        bool ok = jj < end;
        int r = rows[ok ? jj : beg];
        float a = as[r] + ad;
        a = a > 0.f ? a : 0.2f * a;
        float w = ok ? __expf(a) : 0.f;
        int cnt = min(32, end - j0);
        int i = 0;
        for (; i + 3 < cnt; i += 4) {
            float w0 = __shfl(w, i, 32);
            float w1 = __shfl(w, i + 1, 32);
            float w2 = __shfl(w, i + 2, 32);
            float w3 = __shfl(w, i + 3, 32);
            int r0 = __shfl(r, i, 32);
            int r1 = __shfl(r, i + 1, 32);
            int r2 = __shfl(r, i + 2, 32);
            int r3 = __shfl(r, i + 3, 32);
            float v0 = __half2float(h2s[(long)r0 * 32 + lane]);
            float v1 = __half2float(h2s[(long)r1 * 32 + lane]);
            float v2 = __half2float(h2s[(long)r2 * 32 + lane]);
            float v3 = __half2float(h2s[(long)r3 * 32 + lane]);
            den += (w0 + w1) + (w2 + w3);
            acc += w0 * v0 + w1 * v1 + w2 * v2 + w3 * v3;
        }
        for (; i < cnt; ++i) {
            float wi = __shfl(w, i, 32);
            int ri = __shfl(r, i, 32);
            den += wi;
            acc += wi * __half2float(h2s[(long)ri * 32 + lane]);
        }
    }
    agg2[((long)e * NN + node) * 32 + lane] = acc / den;
}

// ---------------- semantic score + softmax over ALL types (layer 2) ----------------
__global__ void score_all_k(const float* __restrict__ colsum, const float* __restrict__ q,
                            float* __restrict__ sattn, int C)
{
    __shared__ float sc[10];
    int tid = threadIdx.x;
    if (tid < 10) {
        float s = 0.f;
        for (int c = 0; c < C; ++c) s += q[c] * colsum[tid * C + c];
        sc[tid] = s / (float)NN;
    }
    __syncthreads();
    if (tid < 4) {
        float mx = -1e30f;
        for (int m = 0; m < 10; ++m) if (d_DST[m] == tid) mx = fmaxf(mx, sc[m]);
        float ex[10];
        float sum = 0.f;
        for (int m = 0; m < 10; ++m) {
            ex[m] = 0.f;
            if (d_DST[m] == tid) { ex[m] = __expf(sc[m] - mx); sum += ex[m]; }
        }
        for (int m = 0; m < 10; ++m) if (d_DST[m] == tid) sattn[m] = ex[m] / sum;
    }
}

// ---------------- final: per-node channel softmax, fp32 out ----------------
__global__ __launch_bounds__(256)
void final_softmax(const float* __restrict__ agg, const float* __restrict__ sattn,
                   float* __restrict__ out)
{
    int gid = blockIdx.x * 256 + threadIdx.x;
    int c = gid & 31;
    int p = gid >> 5;
    if (p >= 4 * NN) return;
    int t = p / NN, n = p - t * NN;
    float f = 0.f;
    for (int m = 0; m < 10; ++m) {
        if (d_DST[m] != t) continue;
        f += sattn[m] * fmaxf(agg[(long)(m * NN + n) * 32 + c], 0.f);
    }
    float mx = f;
#pragma unroll
    for (int off = 1; off < 32; off <<= 1) mx = fmaxf(mx, __shfl_xor(mx, off, 64));
    float ex = __expf(f - mx);
    float sm = ex;
#pragma unroll
    for (int off = 1; off < 32; off <<= 1) sm += __shfl_xor(sm, off, 64);
    out[(long)(t * NN + n) * 32 + c] = ex / sm;
}

extern "C" void kernel_launch(void* const* d_in, const int* in_sizes, int n_in,
                              void* d_out, int out_size, void* d_ws, size_t ws_size,
                              hipStream_t stream) {
    const float* x[4] = {
        (const float*)d_in[0], (const float*)d_in[1],
        (const float*)d_in[2], (const float*)d_in[3]};
    const int* edges = (const int*)d_in[4];
    const float* W1    = (const float*)d_in[5];
    const float* b1    = (const float*)d_in[6];
    const float* att1s = (const float*)d_in[7];
    const float* att1d = (const float*)d_in[8];
    const float* k1W   = (const float*)d_in[9];
    const float* k1b   = (const float*)d_in[10];
    const float* q1    = (const float*)d_in[11];
    const float* W2    = (const float*)d_in[12];
    const float* b2    = (const float*)d_in[13];
    const float* att2s = (const float*)d_in[14];
    const float* att2d = (const float*)d_in[15];
    const float* k2W   = (const float*)d_in[16];
    const float* k2b   = (const float*)d_in[17];
    const float* q2    = (const float*)d_in[18];

    // ---- workspace layout (floats), peak ~175 MB ----
    float* W = (float*)d_ws;
    // region 0 (15,360,000 floats): h1h fp16 during layer 1; layer-2 overlay after
    __half* h1h    = (__half*)W;
    float* slots   = W + 15360000;           // 5 x 3,840,000 = 19,200,000
    float* asrc1   = W + 34560000;           //  2,400,000
    float* adst1   = W + 36960000;           //  2,400,000
    float* colsum1 = W + 39360000;           //      1,280
    float* sattn1  = W + 39361280;           //         16
    float* colsum2 = W + 39361296;           //        320
    float* sattn2  = W + 39361616;           //         16
    int*   csr_off = (int*)(W + 39361640);   //    300,010 ints
    int*   csr_row = csr_off + 300016;       //  4,000,000 ints
    // CSR-build scratch overlays the slots region (dead until gather_agg1):
    unsigned* binned = (unsigned*)(W + 15360000); // 10*59*12288 = 7,249,920 u32
    int*   binCur  = (int*)(W + 15360000 + 7249920); // 590 ints (bucket cursors)
    int*   bbase   = binCur + 640;                   // 590 ints (bucket CSR bases)
    // layer-2 overlay into region 0 (h1h dead after layer-1 gathers):
    __half* h2h    = (__half*)W;             //  3,840,000 halves = 1,920,000 float-slots
    float* agg2    = W + 3840000;            //  9,600,000
    float* asrc2   = W + 13440000;           //    300,000
    float* adst2   = W + 13740000;           //    300,000

    const long SLOT = 3840000;  // NN*128
    auto slot_p = [&](int i) { return slots + (long)i * SLOT; };

    // ---- CSR build (count-free; offsets derived inside buckets) ----
    init_bincur<<<3, 256, 0, stream>>>(binCur);
    csr_binA<<<BPR * 10, 256, 0, stream>>>(edges, binCur, binned);
    bucket_scan<<<10, 64, 0, stream>>>(binCur, bbase, csr_off);
    csr_binB<<<NBUCK * 10, 256, 0, stream>>>(binCur, bbase, binned, csr_off, csr_row);

    hipMemsetAsync(colsum1, 0, 1632L * 4, stream);

    // layer-1 projection (MFMA): h1h[t] = fp16( x[t] @ W1[t] + b1[t] )
    for (int t = 0; t < 4; ++t) {
        mgemm_k<64><<<dim3(469, 2, 1), 256, 0, stream>>>(
            x[t], 0, W1 + (long)t * 256 * 128, 0, b1 + t * 128, 0,
            (float*)(h1h + (long)t * NN * 128), 0, NN, 256, 128, 0, 2);
    }

    attn_dots1<<<30000, 256, 0, stream>>>(h1h, att1s, att1d, asrc1, adst1);

    // per-dst-type schedule
    const int SRC[10] = {0,1,2,3,0,1,2,1,3,1};
    struct TypePlan { int t; int cnt; int rels[4]; int sl[4]; int outsl; };
    const TypePlan plan[4] = {
        {1, 4, {1,4,6,8}, {0,1,2,3}, 3},   // h1f[1] = slot3
        {2, 2, {2,7,0,0}, {0,1,0,0}, 1},   // h1f[2] = slot1
        {0, 2, {0,5,0,0}, {0,2,0,0}, 2},   // h1f[0] = slot2
        {3, 2, {3,9,0,0}, {0,4,0,0}, 4},   // h1f[3] = slot4
    };
    float* h1f[4];

    for (int p = 0; p < 4; ++p) {
        const TypePlan& tp = plan[p];
        for (int j = 0; j < tp.cnt; ++j) {
            int e = tp.rels[j];
            gather_agg1<<<7500, 256, 0, stream>>>(
                csr_off + e * (NN + 1), csr_row + (long)e * NE,
                asrc1 + (long)e * NN * 8, adst1 + (long)e * NN * 8,
                h1h + (long)SRC[e] * NN * 128, slot_p(tp.sl[j]));
        }
        for (int j = 0; j < tp.cnt; ++j) {
            int e = tp.rels[j];
            mgemm_k<64><<<dim3(469, 2, 1), 256, 0, stream>>>(
                slot_p(tp.sl[j]), 0, k1W, 0, k1b, 0,
                colsum1 + (long)e * 128, 0, NN, 128, 128, 1, 1);
        }
        score_t_k<<<1, 32, 0, stream>>>(colsum1, q1, sattn1, 128, tp.t);
        fusion_t<<<3750, 256, 0, stream>>>(
            slot_p(tp.sl[0]), slot_p(tp.sl[1]),
            slot_p(tp.sl[tp.cnt > 2 ? 2 : 0]), slot_p(tp.sl[tp.cnt > 3 ? 3 : 0]),
            tp.cnt, tp.rels[0], tp.rels[1], tp.rels[2], tp.rels[3],
            sattn1, slot_p(tp.outsl));
        h1f[tp.t] = slot_p(tp.outsl);
    }

    // ---- layer 2 (region 0 layer-1 contents dead now; overlay) ----
    for (int t = 0; t < 4; ++t) {
        mgemm_k<32><<<dim3(469, 1, 1), 256, 0, stream>>>(
            h1f[t], 0, W2 + (long)t * 128 * 32, 0, b2 + t * 32, 0,
            (float*)(h2h + (long)t * NN * 32), 0, NN, 128, 32, 0, 2);
    }

    attn_dots2<<<37500, 256, 0, stream>>>(h2h, att2s, att2d, asrc2, adst2);
    gather_agg2<<<dim3(3750, 10), 256, 0, stream>>>(
        csr_off, csr_row, h2h, asrc2, adst2, agg2);

    mgemm_k<32><<<dim3(469, 1, 10), 256, 0, stream>>>(
        agg2, 960000L, k2W, 0, k2b, 0, colsum2, 32L, NN, 32, 32, 1, 1);
    score_all_k<<<1, 64, 0, stream>>>(colsum2, q2, sattn2, 32);
    final_softmax<<<15000, 256, 0, stream>>>(agg2, sattn2, (float*)d_out);
}

// Round 7
// 801.800 us; speedup vs baseline: 1.6190x; 1.3298x over previous
//
#include <hip/hip_runtime.h>
#include <hip/hip_fp16.h>

#define NN 30000
#define NE 400000
#define NBUCK 59     // ceil(30000/512)
#define BPR 98       // blocks per relation in csr_binA: ceil(400000/4096)
#define EPB 4096     // edges per block in csr_binA
#define CAPREG 12288 // fixed slots per (rel,bucket) in binned scratch (mean 6827, sigma 82)
#define BCAP 12288   // LDS sort capacity in csr_binB

__constant__ int d_SRC[10] = {0,1,2,3,0,1,2,1,3,1};
__constant__ int d_DST[10] = {0,1,2,3,1,0,1,2,1,3};
// gather_agg2 relation order grouped by src type (L2 slice reuse)
__constant__ int d_RORD[10] = {1,5,7,9,0,4,2,6,3,8};
// gather_agg1_all relation order grouped by src type: srcs 0,0,1,1,1,1,2,2,3,3
__constant__ int d_GORD[10] = {0,4,1,5,7,9,2,6,3,8};
// fusion tables: per dst type, relations ending there
__constant__ int d_FCNT[4] = {2,4,2,2};
__constant__ int d_FREL[4][4] = {{0,5,0,0},{1,4,6,8},{2,7,0,0},{3,9,0,0}};

typedef _Float16 f16x8 __attribute__((ext_vector_type(8)));
typedef float f32x4 __attribute__((ext_vector_type(4)));

// ---------------- MFMA GEMM: C[M,N] = act(A)[M,K] @ B[K,N] + bias ----
// A fp32 (AF16=false) or fp16 (AF16=true) in HBM; fp16 MFMA operands, fp32 accumulate.
// epi=0: store C fp32. epi=1: tanh + column-sum -> atomicAdd C[N]. epi=2: store fp16.
// sA/sC are strides in A-elements / floats respectively (per z).
template<int BN, bool AF16>
__global__ __launch_bounds__(256)
void mgemm_k(const float* __restrict__ A, long sA,
             const float* __restrict__ B, long sB,
             const float* __restrict__ bias, long sBias,
             float* __restrict__ C, long sC,
             int M, int K, int N, int relu_a, int epi)
{
    constexpr int BM = 64, BK = 32;
    constexpr int NF = BN / 16;       // 16x16 frags per wave
    constexpr int LDK = BK + 8;       // padded LDS leading dim (halves)
    const int z = blockIdx.z;
    const _Float16* __restrict__ Ah = (const _Float16*)A;
    if constexpr (AF16) Ah += (long)z * sA; else A += (long)z * sA;
    B += (long)z * sB;
    bias += (long)z * sBias;
    C += (long)z * sC;
    const int m0 = blockIdx.x * BM;
    const int n0 = blockIdx.y * BN;
    const int tid = threadIdx.x;
    const int wv = tid >> 6;
    const int l  = tid & 63;
    const int fm = l & 15;
    const int fg = l >> 4;

    __shared__ _Float16 As[BM][LDK];
    __shared__ _Float16 Bs[BN][LDK];
    __shared__ float red[4][BN];

    f32x4 acc[NF];
#pragma unroll
    for (int f = 0; f < NF; ++f) acc[f] = (f32x4){0.f, 0.f, 0.f, 0.f};

    const int arow = tid >> 2;          // 0..63
    const int akc  = (tid & 3) << 3;    // 0,8,16,24
    const int grow = m0 + arow;

    for (int k0 = 0; k0 < K; k0 += BK) {
        // ---- A stage ----
        f16x8 ap;
        if (grow < M) {
            if constexpr (AF16) {
                ap = *(const f16x8*)(Ah + (long)grow * K + k0 + akc);
                if (relu_a) {
#pragma unroll
                    for (int j = 0; j < 8; ++j)
                        ap[j] = ap[j] > (_Float16)0.f ? ap[j] : (_Float16)0.f;
                }
            } else {
                const float* aq = A + (long)grow * K + k0 + akc;
                float4 u0 = *(const float4*)aq;
                float4 u1 = *(const float4*)(aq + 4);
                float v[8] = {u0.x, u0.y, u0.z, u0.w, u1.x, u1.y, u1.z, u1.w};
                if (relu_a) {
#pragma unroll
                    for (int j = 0; j < 8; ++j) v[j] = fmaxf(v[j], 0.f);
                }
#pragma unroll
                for (int j = 0; j < 8; ++j) ap[j] = (_Float16)v[j];
            }
        } else {
#pragma unroll
            for (int j = 0; j < 8; ++j) ap[j] = (_Float16)0.f;
        }
        *(f16x8*)&As[arow][akc] = ap;

        // ---- B stage: transpose to Bs[n][k] (fp16) ----
        if constexpr (BN == 64) {
            const int bk = tid >> 4;
            const int bn = (tid & 15) << 2;
#pragma unroll
            for (int kk = 0; kk < 2; ++kk) {
                int kr = bk + kk * 16;
                float4 u = *(const float4*)(B + (long)(k0 + kr) * N + n0 + bn);
                Bs[bn + 0][kr] = (_Float16)u.x;
                Bs[bn + 1][kr] = (_Float16)u.y;
                Bs[bn + 2][kr] = (_Float16)u.z;
                Bs[bn + 3][kr] = (_Float16)u.w;
            }
        } else {                                 // BN == 32
            const int bk = tid >> 3;
            const int bn = (tid & 7) << 2;
            float4 u = *(const float4*)(B + (long)(k0 + bk) * N + n0 + bn);
            Bs[bn + 0][bk] = (_Float16)u.x;
            Bs[bn + 1][bk] = (_Float16)u.y;
            Bs[bn + 2][bk] = (_Float16)u.z;
            Bs[bn + 3][bk] = (_Float16)u.w;
        }
        __syncthreads();

        f16x8 a = *(const f16x8*)&As[wv * 16 + fm][fg * 8];
#pragma unroll
        for (int f = 0; f < NF; ++f) {
            f16x8 b = *(const f16x8*)&Bs[f * 16 + fm][fg * 8];
            acc[f] = __builtin_amdgcn_mfma_f32_16x16x32_f16(a, b, acc[f], 0, 0, 0);
        }
        __syncthreads();
    }

    // ---- epilogues (C/D layout: col = l&15, row = 4*(l>>4)+i) ----
    if (epi == 0) {
#pragma unroll
        for (int f = 0; f < NF; ++f) {
            float bz = bias[n0 + f * 16 + fm];
#pragma unroll
            for (int i = 0; i < 4; ++i) {
                int gr = m0 + wv * 16 + fg * 4 + i;
                if (gr < M) C[(long)gr * N + n0 + f * 16 + fm] = acc[f][i] + bz;
            }
        }
    } else if (epi == 2) {
        __half* Ch = (__half*)C;
#pragma unroll
        for (int f = 0; f < NF; ++f) {
            float bz = bias[n0 + f * 16 + fm];
#pragma unroll
            for (int i = 0; i < 4; ++i) {
                int gr = m0 + wv * 16 + fg * 4 + i;
                if (gr < M) Ch[(long)gr * N + n0 + f * 16 + fm] = __float2half(acc[f][i] + bz);
            }
        }
    } else {
#pragma unroll
        for (int f = 0; f < NF; ++f) {
            float bz = bias[n0 + f * 16 + fm];
            float s = 0.f;
#pragma unroll
            for (int i = 0; i < 4; ++i) {
                int gr = m0 + wv * 16 + fg * 4 + i;
                if (gr < M) s += tanhf(acc[f][i] + bz);
            }
            s += __shfl_xor(s, 16, 64);
            s += __shfl_xor(s, 32, 64);
            if (fg == 0) red[wv][f * 16 + fm] = s;
        }
        __syncthreads();
        if (tid < BN) {
            float s = red[0][tid] + red[1][tid] + red[2][tid] + red[3][tid];
            unsafeAtomicAdd(&C[n0 + tid], s);
        }
    }
}

// ---------------- CSR build (count-free: histogram derived from binning) ----------
__global__ __launch_bounds__(256)
void init_bincur(int* __restrict__ binCur)
{
    int i = blockIdx.x * 256 + threadIdx.x;
    if (i < 10 * NBUCK) binCur[i] = (i % NBUCK) * CAPREG;
}

__global__ __launch_bounds__(256)
void csr_binA(const int* __restrict__ edges, int* __restrict__ binCur,
              unsigned* __restrict__ binned)
{
    __shared__ int lcnt[NBUCK];
    __shared__ int gbase[NBUCK];
    int rel = blockIdx.x / BPR;
    int blk = blockIdx.x - rel * BPR;
    int base = blk * EPB;
    int tid = threadIdx.x;
    for (int b = tid; b < NBUCK; b += 256) lcnt[b] = 0;
    __syncthreads();
    const int* er = edges + (long)rel * 2 * NE;
    const int* ec = er + NE;
    unsigned pk[16];
    unsigned mt[16];
#pragma unroll
    for (int k = 0; k < 16; ++k) {
        int i = base + k * 256 + tid;
        if (i < NE) {
            int r = er[i];
            int c = ec[i];
            int b = c >> 9;
            int lo = atomicAdd(&lcnt[b], 1);
            pk[k] = ((unsigned)c << 15) | (unsigned)r;
            mt[k] = ((unsigned)b << 16) | (unsigned)lo;
        } else {
            mt[k] = 0xFFFFFFFFu;
        }
    }
    __syncthreads();
    if (tid < NBUCK) gbase[tid] = atomicAdd(&binCur[rel * NBUCK + tid], lcnt[tid]);
    __syncthreads();
    unsigned* bn = binned + (long)rel * NBUCK * CAPREG;
#pragma unroll
    for (int k = 0; k < 16; ++k) {
        if (mt[k] != 0xFFFFFFFFu) {
            int b = mt[k] >> 16;
            int lo = mt[k] & 0xFFFF;
            bn[gbase[b] + lo] = pk[k];
        }
    }
}

__global__ __launch_bounds__(64)
void bucket_scan(const int* __restrict__ binCur, int* __restrict__ bbase,
                 int* __restrict__ off_all)
{
    int rel = blockIdx.x;
    int t = threadIdx.x;
    __shared__ int c[64];
    int v = (t < NBUCK) ? (binCur[rel * NBUCK + t] - t * CAPREG) : 0;
    c[t] = v;
    __syncthreads();
    for (int d = 1; d < 64; d <<= 1) {
        int u = (t >= d) ? c[t - d] : 0;
        __syncthreads();
        c[t] += u;
        __syncthreads();
    }
    if (t < NBUCK) bbase[rel * NBUCK + t] = c[t] - v;
    if (t == 0) off_all[rel * (NN + 1) + NN] = NE;
}

__global__ __launch_bounds__(256)
void csr_binB(const int* __restrict__ binCur, const int* __restrict__ bbase,
              const unsigned* __restrict__ binned,
              int* __restrict__ off_all, int* __restrict__ rows)
{
    __shared__ int cntS[512];
    __shared__ int lcur[512];
    __shared__ int part[256];
    __shared__ int buf[BCAP];
    int rel = blockIdx.x / NBUCK;
    int bkt = blockIdx.x - rel * NBUCK;
    const unsigned* bn = binned + ((long)rel * NBUCK + bkt) * CAPREG;
    int* off = off_all + rel * (NN + 1);
    int* rw = rows + (long)rel * NE;
    int cnt = binCur[rel * NBUCK + bkt] - bkt * CAPREG;
    int gbase = bbase[rel * NBUCK + bkt];
    int nb0 = bkt << 9;
    int nb1 = min(nb0 + 512, NN);
    int nloc = nb1 - nb0;
    int tid = threadIdx.x;

    cntS[tid] = 0; cntS[tid + 256] = 0;
    __syncthreads();
    for (int j = tid; j < cnt; j += 256) {
        int c = (int)(bn[j] >> 15);
        atomicAdd(&cntS[c - nb0], 1);
    }
    __syncthreads();
    int c0 = cntS[2 * tid], c1 = cntS[2 * tid + 1];
    part[tid] = c0 + c1;
    __syncthreads();
    for (int d = 1; d < 256; d <<= 1) {
        int u = (tid >= d) ? part[tid - d] : 0;
        __syncthreads();
        part[tid] += u;
        __syncthreads();
    }
    int pre = (tid == 0) ? 0 : part[tid - 1];
    cntS[2 * tid] = pre;
    cntS[2 * tid + 1] = pre + c0;
    __syncthreads();
    for (int i = tid; i < nloc; i += 256) off[nb0 + i] = gbase + cntS[i];
    lcur[tid] = cntS[tid]; lcur[tid + 256] = cntS[tid + 256];
    __syncthreads();
    if (cnt <= BCAP) {
        for (int j = tid; j < cnt; j += 256) {
            unsigned p = bn[j];
            int r = (int)(p & 0x7FFF);
            int c = (int)(p >> 15);
            int pos = atomicAdd(&lcur[c - nb0], 1);
            buf[pos] = r;
        }
        __syncthreads();
        for (int i = tid; i < cnt; i += 256) rw[gbase + i] = buf[i];
    } else {
        for (int j = tid; j < cnt; j += 256) {
            unsigned p = bn[j];
            int r = (int)(p & 0x7FFF);
            int c = (int)(p >> 15);
            int pos = atomicAdd(&lcur[c - nb0], 1);
            rw[gbase + pos] = r;
        }
    }
}

// ---------------- layer-1 attention dots (h1 in fp16) ----------------
__global__ __launch_bounds__(256)
void attn_dots1(const __half* __restrict__ h1h,
                const float* __restrict__ att_src,
                const float* __restrict__ att_dst,
                float* __restrict__ asrc, float* __restrict__ adst)
{
    int gid = blockIdx.x * 256 + threadIdx.x;
    int wave = gid >> 6;
    int lane = gid & 63;
    if (wave >= 4 * NN) return;
    int t = wave / NN;
    int n = wave - t * NN;
    __half2 hh = *(const __half2*)&h1h[(long)(t * NN + n) * 128 + 2 * lane];
    float2 hv = __half22float2(hh);
    const int SRCc[10] = {0,1,2,3,0,1,2,1,3,1};
    const int DSTc[10] = {0,1,2,3,1,0,1,2,1,3};
#pragma unroll
    for (int e = 0; e < 10; ++e) {
        if (SRCc[e] == t) {
            float2 av = *(const float2*)&att_src[e * 128 + 2 * lane];
            float p = hv.x * av.x + hv.y * av.y;
#pragma unroll
            for (int off = 1; off < 8; off <<= 1) p += __shfl_xor(p, off, 64);
            if ((lane & 7) == 0) asrc[(long)(e * NN + n) * 8 + (lane >> 3)] = p;
        }
        if (DSTc[e] == t) {
            float2 bv = *(const float2*)&att_dst[e * 128 + 2 * lane];
            float p = hv.x * bv.x + hv.y * bv.y;
#pragma unroll
            for (int off = 1; off < 8; off <<= 1) p += __shfl_xor(p, off, 64);
            if ((lane & 7) == 0) adst[(long)(e * NN + n) * 8 + (lane >> 3)] = p;
        }
    }
}

// ---------------- layer-1 gather-aggregate: ALL relations, one dispatch ------------
// y = src-grouped relation; two-phase rounds of 8 edges (weights computed once);
// output fp16.
__global__ __launch_bounds__(256)
void gather_agg1_all(const int* __restrict__ csr_off, const int* __restrict__ csr_rows,
                     const float* __restrict__ asrc1, const float* __restrict__ adst1,
                     const __half* __restrict__ h1h, __half* __restrict__ slots16)
{
    int e = d_GORD[blockIdx.y];
    int node = blockIdx.x * 4 + (threadIdx.x >> 6);
    int lane = threadIdx.x & 63;
    if (node >= NN) return;
    const int* off = csr_off + e * (NN + 1);
    const int* rows = csr_rows + (long)e * NE;
    const float* asrc_e = asrc1 + (long)e * NN * 8;
    const float* adst_e = adst1 + (long)e * NN * 8;
    const __half* h1s = h1h + (long)d_SRC[e] * NN * 128;
    __half* out = slots16 + (long)e * NN * 128;

    const int hB = lane >> 3;     // head owning this lane's 2 value channels
    const int hA = lane & 7;      // head this lane computes weights for (phase A)
    const int eA = lane >> 3;     // edge-in-round this lane computes weights for
    int beg = off[node], end = off[node + 1];
    float adA = adst_e[node * 8 + hA];
    float den = 1e-16f;
    float accx = 0.f, accy = 0.f;
    for (int j0 = beg; j0 < end; j0 += 8) {
        int jj = j0 + eA;
        bool ok = jj < end;
        int r = rows[ok ? jj : beg];
        float a = asrc_e[r * 8 + hA] + adA;
        a = a > 0.f ? a : 0.2f * a;
        float w = ok ? __expf(a) : 0.f;
        int cnt = end - j0;
        if (cnt >= 8) {
#pragma unroll
            for (int i = 0; i < 8; ++i) {
                float wi = __shfl(w, i * 8 + hB, 64);
                int ri = __shfl(r, i * 8, 64);
                float2 v = __half22float2(*(const __half2*)&h1s[(long)ri * 128 + 2 * lane]);
                den += wi;
                accx += wi * v.x;
                accy += wi * v.y;
            }
        } else {
            for (int i = 0; i < cnt; ++i) {
                float wi = __shfl(w, i * 8 + hB, 64);
                int ri = __shfl(r, i * 8, 64);
                float2 v = __half22float2(*(const __half2*)&h1s[(long)ri * 128 + 2 * lane]);
                den += wi;
                accx += wi * v.x;
                accy += wi * v.y;
            }
        }
    }
    float inv = 1.0f / den;
    *(__half2*)&out[(long)node * 128 + 2 * lane] = __floats2half2_rn(accx * inv, accy * inv);
}

// ---------------- per-type fusion (batched): out = elu( sum sattn[e]*relu(slot_e) ) --
__global__ __launch_bounds__(256)
void fusion_all(const __half* __restrict__ slots16, const float* __restrict__ sattn,
                __half* __restrict__ h1f)
{
    int t = blockIdx.y;
    int idx = blockIdx.x * 256 + threadIdx.x;
    if (idx >= NN * 32) return;
    int c4 = idx & 31;
    int n = idx >> 5;
    long off = (long)n * 128 + c4 * 4;
    int cnt = d_FCNT[t];
    float o0 = 0.f, o1 = 0.f, o2 = 0.f, o3 = 0.f;
    for (int j = 0; j < cnt; ++j) {
        int e = d_FREL[t][j];
        float w = sattn[e];
        const __half* p = slots16 + (long)e * NN * 128 + off;
        float2 v01 = __half22float2(*(const __half2*)p);
        float2 v23 = __half22float2(*(const __half2*)(p + 2));
        o0 += w * fmaxf(v01.x, 0.f);
        o1 += w * fmaxf(v01.y, 0.f);
        o2 += w * fmaxf(v23.x, 0.f);
        o3 += w * fmaxf(v23.y, 0.f);
    }
    o0 = o0 > 0.f ? o0 : __expf(o0) - 1.f;
    o1 = o1 > 0.f ? o1 : __expf(o1) - 1.f;
    o2 = o2 > 0.f ? o2 : __expf(o2) - 1.f;
    o3 = o3 > 0.f ? o3 : __expf(o3) - 1.f;
    __half* q = h1f + (long)t * NN * 128 + off;
    *(__half2*)q = __floats2half2_rn(o0, o1);
    *(__half2*)(q + 2) = __floats2half2_rn(o2, o3);
}

// ---------------- layer-2 attention dots (h2 in fp16; 1 head, 32 ch) --------------
__global__ __launch_bounds__(256)
void attn_dots2(const __half* __restrict__ h2h,
                const float* __restrict__ att_src,
                const float* __restrict__ att_dst,
                float* __restrict__ asrc, float* __restrict__ adst)
{
    int gid = blockIdx.x * 256 + threadIdx.x;
    int p = gid >> 5;
    int l = gid & 31;
    if (p >= 10 * NN) return;
    int e = p / NN, n = p - e * NN;
    int s = d_SRC[e], d = d_DST[e];
    float hs = __half2float(h2h[(long)(s * NN + n) * 32 + l]);
    float hd = __half2float(h2h[(long)(d * NN + n) * 32 + l]);
    float ps = hs * att_src[e * 32 + l];
    float pd = hd * att_dst[e * 32 + l];
#pragma unroll
    for (int off = 1; off < 32; off <<= 1) {
        ps += __shfl_xor(ps, off, 64);
        pd += __shfl_xor(pd, off, 64);
    }
    if (l == 0) { asrc[e * NN + n] = ps; adst[e * NN + n] = pd; }
}

// ---------------- layer-2 gather-aggregate: in-wave two-phase rounds --------------
__global__ __launch_bounds__(256)
void gather_agg2(const int* __restrict__ csr_off, const int* __restrict__ csr_rows,
                 const __half* __restrict__ h2h,
                 const float* __restrict__ asrc, const float* __restrict__ adst,
                 float* __restrict__ agg2)
{
    int e = d_RORD[blockIdx.y];
    int node = blockIdx.x * 8 + (threadIdx.x >> 5);
    int lane = threadIdx.x & 31;
    if (node >= NN) return;
    const int* off = csr_off + e * (NN + 1);
    const int* rows = csr_rows + (long)e * NE;
    const __half* h2s = h2h + (long)d_SRC[e] * NN * 32;
    const float* as = asrc + e * NN;
    float ad = adst[e * NN + node];
    int beg = off[node], end = off[node + 1];
    float den = 1e-16f;
    float acc = 0.f;
    for (int j0 = beg; j0 < end; j0 += 32) {
        int jj = j0 + lane;
        bool ok = jj < end;
        int r = rows[ok ? jj : beg];
        float a = as[r] + ad;
        a = a > 0.f ? a : 0.2f * a;
        float w = ok ? __expf(a) : 0.f;
        int cnt = min(32, end - j0);
        int i = 0;
        for (; i + 3 < cnt; i += 4) {
            float w0 = __shfl(w, i, 32);
            float w1 = __shfl(w, i + 1, 32);
            float w2 = __shfl(w, i + 2, 32);
            float w3 = __shfl(w, i + 3, 32);
            int r0 = __shfl(r, i, 32);
            int r1 = __shfl(r, i + 1, 32);
            int r2 = __shfl(r, i + 2, 32);
            int r3 = __shfl(r, i + 3, 32);
            float v0 = __half2float(h2s[(long)r0 * 32 + lane]);
            float v1 = __half2float(h2s[(long)r1 * 32 + lane]);
            float v2 = __half2float(h2s[(long)r2 * 32 + lane]);
            float v3 = __half2float(h2s[(long)r3 * 32 + lane]);
            den += (w0 + w1) + (w2 + w3);
            acc += w0 * v0 + w1 * v1 + w2 * v2 + w3 * v3;
        }
        for (; i < cnt; ++i) {
            float wi = __shfl(w, i, 32);
            int ri = __shfl(r, i, 32);
            den += wi;
            acc += wi * __half2float(h2s[(long)ri * 32 + lane]);
        }
    }
    agg2[((long)e * NN + node) * 32 + lane] = acc / den;
}

// ---------------- semantic score + softmax over ALL types ----------------
__global__ void score_all_k(const float* __restrict__ colsum, const float* __restrict__ q,
                            float* __restrict__ sattn, int C)
{
    __shared__ float sc[10];
    int tid = threadIdx.x;
    if (tid < 10) {
        float s = 0.f;
        for (int c = 0; c < C; ++c) s += q[c] * colsum[tid * C + c];
        sc[tid] = s / (float)NN;
    }
    __syncthreads();
    if (tid < 4) {
        float mx = -1e30f;
        for (int m = 0; m < 10; ++m) if (d_DST[m] == tid) mx = fmaxf(mx, sc[m]);
        float ex[10];
        float sum = 0.f;
        for (int m = 0; m < 10; ++m) {
            ex[m] = 0.f;
            if (d_DST[m] == tid) { ex[m] = __expf(sc[m] - mx); sum += ex[m]; }
        }
        for (int m = 0; m < 10; ++m) if (d_DST[m] == tid) sattn[m] = ex[m] / sum;
    }
}

// ---------------- final: per-node channel softmax, fp32 out ----------------
__global__ __launch_bounds__(256)
void final_softmax(const float* __restrict__ agg, const float* __restrict__ sattn,
                   float* __restrict__ out)
{
    int gid = blockIdx.x * 256 + threadIdx.x;
    int c = gid & 31;
    int p = gid >> 5;
    if (p >= 4 * NN) return;
    int t = p / NN, n = p - t * NN;
    float f = 0.f;
    for (int m = 0; m < 10; ++m) {
        if (d_DST[m] != t) continue;
        f += sattn[m] * fmaxf(agg[(long)(m * NN + n) * 32 + c], 0.f);
    }
    float mx = f;
#pragma unroll
    for (int off = 1; off < 32; off <<= 1) mx = fmaxf(mx, __shfl_xor(mx, off, 64));
    float ex = __expf(f - mx);
    float sm = ex;
#pragma unroll
    for (int off = 1; off < 32; off <<= 1) sm += __shfl_xor(sm, off, 64);
    out[(long)(t * NN + n) * 32 + c] = ex / sm;
}

extern "C" void kernel_launch(void* const* d_in, const int* in_sizes, int n_in,
                              void* d_out, int out_size, void* d_ws, size_t ws_size,
                              hipStream_t stream) {
    const float* x[4] = {
        (const float*)d_in[0], (const float*)d_in[1],
        (const float*)d_in[2], (const float*)d_in[3]};
    const int* edges = (const int*)d_in[4];
    const float* W1    = (const float*)d_in[5];
    const float* b1    = (const float*)d_in[6];
    const float* att1s = (const float*)d_in[7];
    const float* att1d = (const float*)d_in[8];
    const float* k1W   = (const float*)d_in[9];
    const float* k1b   = (const float*)d_in[10];
    const float* q1    = (const float*)d_in[11];
    const float* W2    = (const float*)d_in[12];
    const float* b2    = (const float*)d_in[13];
    const float* att2s = (const float*)d_in[14];
    const float* att2d = (const float*)d_in[15];
    const float* k2W   = (const float*)d_in[16];
    const float* k2b   = (const float*)d_in[17];
    const float* q2    = (const float*)d_in[18];

    // ---- workspace layout (floats), peak ~175 MB ----
    float* W = (float*)d_ws;
    // region 0 [0, 15.36M floats):
    //   layer 1: h1h fp16 [4][NN][128] = 7.68M float-slots at offset 0
    //   after fusion: h1f fp16 [4][NN][128] overlays offset 0 (h1h dead)
    //                 h2h fp16 [4][NN][32] at offset 7.68M (0.96M float-slots)
    __half* h1h    = (__half*)W;
    __half* h1f    = (__half*)W;
    __half* h2h    = (__half*)(W + 7680000);
    // slots region [15.36M, 34.56M): slots16 fp16 [10][NN][128] = 19.2M float-slots;
    //   CSR binned scratch overlays it before the gathers; agg2 overlays after fusion.
    __half* slots16 = (__half*)(W + 15360000);
    float* agg2    = W + 15360000;           // 9.6M floats (slots16 dead after fusion)
    unsigned* binned = (unsigned*)(W + 15360000); // 10*59*12288 u32
    int*   binCur  = (int*)(W + 15360000 + 7249920);
    int*   bbase   = binCur + 640;
    float* asrc1   = W + 34560000;           // 2.4M
    float* adst1   = W + 36960000;           // 2.4M (asrc2/adst2 overlay after layer 1)
    float* asrc2   = W + 36960000;           // 0.3M
    float* adst2   = W + 37260000;           // 0.3M
    float* colsum1 = W + 39360000;           // 1,280
    float* sattn1  = W + 39361280;           // 16
    float* colsum2 = W + 39361296;           // 320
    float* sattn2  = W + 39361616;           // 16
    int*   csr_off = (int*)(W + 39361640);   // 300,010 ints
    int*   csr_row = csr_off + 300016;       // 4,000,000 ints

    // ---- CSR build ----
    init_bincur<<<3, 256, 0, stream>>>(binCur);
    csr_binA<<<BPR * 10, 256, 0, stream>>>(edges, binCur, binned);
    bucket_scan<<<10, 64, 0, stream>>>(binCur, bbase, csr_off);
    csr_binB<<<NBUCK * 10, 256, 0, stream>>>(binCur, bbase, binned, csr_off, csr_row);

    hipMemsetAsync(colsum1, 0, 1632L * 4, stream);

    // layer-1 projection (MFMA): h1h[t] = fp16( x[t] @ W1[t] + b1[t] )
    for (int t = 0; t < 4; ++t) {
        mgemm_k<64, false><<<dim3(469, 2, 1), 256, 0, stream>>>(
            x[t], 0, W1 + (long)t * 256 * 128, 0, b1 + t * 128, 0,
            (float*)(h1h + (long)t * NN * 128), 0, NN, 256, 128, 0, 2);
    }

    attn_dots1<<<30000, 256, 0, stream>>>(h1h, att1s, att1d, asrc1, adst1);

    // ALL 10 relation gathers in one dispatch (src-grouped), fp16 output
    gather_agg1_all<<<dim3(7500, 10), 256, 0, stream>>>(
        csr_off, csr_row, asrc1, adst1, h1h, slots16);

    // batched colsum over all 10 relations (fp16 A)
    mgemm_k<64, true><<<dim3(469, 2, 10), 256, 0, stream>>>(
        (const float*)slots16, (long)NN * 128, k1W, 0, k1b, 0,
        colsum1, 128, NN, 128, 128, 1, 1);
    score_all_k<<<1, 64, 0, stream>>>(colsum1, q1, sattn1, 128);

    // batched fusion over 4 dst types -> h1f fp16
    fusion_all<<<dim3(3750, 4), 256, 0, stream>>>(slots16, sattn1, h1f);

    // layer-2 projection (batched z=4, fp16 A): h2h[t] = fp16( h1f[t] @ W2[t] + b2[t] )
    mgemm_k<32, true><<<dim3(469, 1, 4), 256, 0, stream>>>(
        (const float*)h1f, (long)NN * 128, W2, 128L * 32, b2, 32,
        (float*)h2h, (long)NN * 16, NN, 128, 32, 0, 2);

    attn_dots2<<<37500, 256, 0, stream>>>(h2h, att2s, att2d, asrc2, adst2);
    gather_agg2<<<dim3(3750, 10), 256, 0, stream>>>(
        csr_off, csr_row, h2h, asrc2, adst2, agg2);

    mgemm_k<32, false><<<dim3(469, 1, 10), 256, 0, stream>>>(
        agg2, 960000L, k2W, 0, k2b, 0, colsum2, 32L, NN, 32, 32, 1, 1);
    score_all_k<<<1, 64, 0, stream>>>(colsum2, q2, sattn2, 32);
    final_softmax<<<15000, 256, 0, stream>>>(agg2, sattn2, (float*)d_out);
}